// Round 1
// baseline (1545.613 us; speedup 1.0000x reference)
//
#include <hip/hip_runtime.h>
#include <cstdint>
#include <cstddef>

#define NN 2048   // nodes
#define NE 4096   // edges
#define NG 128    // graphs
#define HD 128    // hidden
#define KH 129    // 128 h rows + 1 bias row
#define BM 64
#define BN 64
#define SK 4
#define KCH 33    // ceil(129/4)

// ---------------- CSR build (deterministic) ----------------
__global__ void k_count(const int* __restrict__ dst, int* __restrict__ counts) {
  int e = blockIdx.x * 256 + threadIdx.x;
  if (e < NE) atomicAdd(&counts[dst[e]], 1);
}

__global__ __launch_bounds__(1024) void k_scan(const int* __restrict__ counts,
                                               int* __restrict__ rowptr) {
  __shared__ int s[NN];
  int t = threadIdx.x;
  s[t] = counts[t];
  s[t + 1024] = counts[t + 1024];
  __syncthreads();
  for (int d = 1; d < NN; d <<= 1) {
    int a0 = s[t], a1 = s[t + 1024];
    int v0 = (t >= d) ? s[t - d] : 0;
    int v1 = (t + 1024 >= d) ? s[t + 1024 - d] : 0;
    __syncthreads();
    s[t] = a0 + v0;
    s[t + 1024] = a1 + v1;
    __syncthreads();
  }
  rowptr[t + 1] = s[t];
  rowptr[t + 1025] = s[t + 1024];
  if (t == 0) rowptr[0] = 0;
}

__global__ __launch_bounds__(1024) void k_fill(const int* __restrict__ dst,
                                               const int* __restrict__ rowptr,
                                               int* __restrict__ elist) {
  __shared__ int sd[NE];
  int t = threadIdx.x;
  for (int i = t; i < NE; i += 1024) sd[i] = dst[i];
  __syncthreads();
  int e = blockIdx.x * 1024 + t;
  int dv = sd[e];
  int rank = 0;
  for (int j = 0; j < e; ++j) rank += (sd[j] == dv) ? 1 : 0;
  elist[rowptr[dv] + rank] = e;   // stable order -> deterministic float sums later
}

__global__ void k_gbounds(const int* __restrict__ batch, int* __restrict__ gstart) {
  int g = threadIdx.x;
  if (g > NG) return;
  int lo = 0, hi = NN;
  while (lo < hi) { int mid = (lo + hi) >> 1; if (batch[mid] < g) lo = mid + 1; else hi = mid; }
  gstart[g] = lo;  // lower_bound on sorted batch; handles empty graphs
}

// ---------------- edge MLP h for all 5 layers ----------------
__global__ void k_hall(const float* __restrict__ ea,
                       const float* __restrict__ w1_0, const float* __restrict__ b1_0,
                       const float* __restrict__ w1_s, const float* __restrict__ b1_s,
                       float* __restrict__ h_edge) {
  int idx = blockIdx.x * 256 + threadIdx.x;   // l*2^19 + e*128 + c
  int c = idx & (HD - 1);
  int e = (idx >> 7) & (NE - 1);
  int l = idx >> 19;
  const float* w1 = (l == 0) ? w1_0 : (w1_s + (size_t)(l - 1) * 4 * HD);
  const float* b1 = (l == 0) ? b1_0 : (b1_s + (size_t)(l - 1) * HD);
  float4 a = *(const float4*)(ea + (size_t)e * 4);
  float v = b1[c] + a.x * w1[c] + a.y * w1[HD + c] + a.z * w1[2 * HD + c] + a.w * w1[3 * HD + c];
  h_edge[idx] = fmaxf(v, 0.f);
}

// ---------------- big fused GEMM: msg = (h (x) x_src) @ W2 ----------------
// Z[e, (k,i)] = h_e[k] * xs_e[i]  (k==128 -> 1.0 to fold b2), W2 row (k,i) = w2[k][i*H+o]
template <int INP, int INR>
__global__ __launch_bounds__(256) void k_msg(
    const float* __restrict__ xsrc, const float* __restrict__ hbuf,
    const float* __restrict__ w2, const float* __restrict__ b2,
    const int* __restrict__ src, float* __restrict__ msgp) {
  __shared__ float xs[INP][BM];   // [i][m]
  __shared__ float hs[KCH][BM];   // [kk][m]
  __shared__ float ws[16][BN];    // [ii][col]
  __shared__ int se[BM];

  const int tid = threadIdx.x;
  const int mb = blockIdx.x, nb = blockIdx.y, sk = blockIdx.z;
  const int e0 = mb * BM, c0 = nb * BN;
  const int k0 = sk * KCH;
  const int k1 = min(k0 + KCH, KH);
  const int kr = k1 - k0;

  if (tid < BM) se[tid] = src[e0 + tid];
  __syncthreads();

  if constexpr (INP == 128) {
    #pragma unroll
    for (int q = 0; q < 8; ++q) {
      int idx = tid + q * 256;
      int m = idx >> 5, c4 = (idx & 31) * 4;
      float4 v = *(const float4*)(xsrc + (size_t)se[m] * INR + c4);
      xs[c4 + 0][m] = v.x; xs[c4 + 1][m] = v.y; xs[c4 + 2][m] = v.z; xs[c4 + 3][m] = v.w;
    }
  } else {
    #pragma unroll
    for (int q = 0; q < 4; ++q) {
      int idx = tid + q * 256;    // 64 m x 16 i
      int m = idx >> 4, i = idx & 15;
      xs[i][m] = (i < INR) ? xsrc[(size_t)se[m] * INR + i] : 0.f;
    }
  }
  for (int idx = tid; idx < KCH * BM; idx += 256) {
    int kk = idx >> 6, m = idx & 63;
    int k = k0 + kk;
    float v = 0.f;
    if (k < 128) v = hbuf[(size_t)(e0 + m) * HD + k];
    else if (k == 128) v = 1.f;
    hs[kk][m] = v;
  }
  __syncthreads();

  const int tm = (tid >> 4) * 4;  // 16 m-groups * 4 rows
  const int tn = (tid & 15) * 4;  // 16 n-groups * 4 cols
  float acc[4][4] = {};

  for (int kk = 0; kk < kr; ++kk) {
    const int k = k0 + kk;
    const float4 hv = *(const float4*)&hs[kk][tm];
    for (int ic = 0; ic < INP; ic += 16) {
      __syncthreads();   // previous ws readers done
      {
        int ii = tid >> 4, c4 = (tid & 15) * 4;
        int i = ic + ii;
        float4 wv = make_float4(0.f, 0.f, 0.f, 0.f);
        if (i < INR) {
          const float* p = (k < 128) ? (w2 + ((size_t)k * INR + i) * HD + c0 + c4)
                                     : (b2 + (size_t)i * HD + c0 + c4);
          wv = *(const float4*)p;
        }
        *(float4*)&ws[ii][c4] = wv;
      }
      __syncthreads();
      #pragma unroll
      for (int ii = 0; ii < 16; ++ii) {
        float4 xv = *(const float4*)&xs[ic + ii][tm];
        float4 wv = *(const float4*)&ws[ii][tn];
        float a0 = hv.x * xv.x, a1 = hv.y * xv.y, a2 = hv.z * xv.z, a3 = hv.w * xv.w;
        acc[0][0] += a0 * wv.x; acc[0][1] += a0 * wv.y; acc[0][2] += a0 * wv.z; acc[0][3] += a0 * wv.w;
        acc[1][0] += a1 * wv.x; acc[1][1] += a1 * wv.y; acc[1][2] += a1 * wv.z; acc[1][3] += a1 * wv.w;
        acc[2][0] += a2 * wv.x; acc[2][1] += a2 * wv.y; acc[2][2] += a2 * wv.z; acc[2][3] += a2 * wv.w;
        acc[3][0] += a3 * wv.x; acc[3][1] += a3 * wv.y; acc[3][2] += a3 * wv.z; acc[3][3] += a3 * wv.w;
      }
    }
  }
  #pragma unroll
  for (int mi = 0; mi < 4; ++mi) {
    float4 v = make_float4(acc[mi][0], acc[mi][1], acc[mi][2], acc[mi][3]);
    *(float4*)(msgp + ((size_t)sk * NE + e0 + tm + mi) * HD + c0 + tn) = v;
  }
}

// ---------------- split-K reduce + scatter-mean ----------------
__global__ void k_aggr(const float* __restrict__ msgp, const int* __restrict__ rowptr,
                       const int* __restrict__ elist, float* __restrict__ aggr) {
  int n = blockIdx.x, t = threadIdx.x;  // 128 threads
  int beg = rowptr[n], end = rowptr[n + 1];
  float v = 0.f;
  for (int j = beg; j < end; ++j) {
    int e = elist[j];
    #pragma unroll
    for (int s = 0; s < SK; ++s) v += msgp[((size_t)s * NE + e) * HD + t];
  }
  aggr[(size_t)n * HD + t] = v / fmaxf((float)(end - beg), 1.f);
}

// ---------------- aggr + x@root + bias -> BN -> ReLU (+residual) ----------------
template <int INR>
__global__ void k_update(const float* __restrict__ aggr, const float* __restrict__ xin,
                         const float* __restrict__ root, const float* __restrict__ bias,
                         const float* __restrict__ bg, const float* __restrict__ bb,
                         const float* __restrict__ bm, const float* __restrict__ bv,
                         const float* __restrict__ h_prev, float* __restrict__ h_out) {
  int n = blockIdx.x, t = threadIdx.x;  // 128 threads
  __shared__ float xr[INR];
  if (t < INR) xr[t] = xin[(size_t)n * INR + t];
  __syncthreads();
  float acc = aggr[(size_t)n * HD + t] + bias[t];
  #pragma unroll 8
  for (int k = 0; k < INR; ++k) acc += xr[k] * root[(size_t)k * HD + t];
  float bn = (acc - bm[t]) * rsqrtf(bv[t] + 1e-5f) * bg[t] + bb[t];
  float r = fmaxf(bn, 0.f);
  h_out[(size_t)n * HD + t] = h_prev ? (h_prev[(size_t)n * HD + t] + r) : r;
}

// ---------------- global mean pool ----------------
__global__ void k_pool(const float* __restrict__ h, const int* __restrict__ gstart,
                       float* __restrict__ pooled) {
  int g = blockIdx.x, t = threadIdx.x;  // 128 threads
  int beg = gstart[g], end = gstart[g + 1];
  float v = 0.f;
  for (int n = beg; n < end; ++n) v += h[(size_t)n * HD + t];
  pooled[(size_t)g * HD + t] = v / fmaxf((float)(end - beg), 1.f);
}

// ---------------- readout MLP ----------------
__global__ void k_readout(const float* __restrict__ pooled,
                          const float* __restrict__ w1, const float* __restrict__ b1,
                          const float* __restrict__ w2, const float* __restrict__ b2,
                          float* __restrict__ out) {
  int g = blockIdx.x, t = threadIdx.x;  // 64 threads = 1 wave
  __shared__ float row[HD];
  row[t] = pooled[(size_t)g * HD + t];
  row[t + 64] = pooled[(size_t)g * HD + t + 64];
  __syncthreads();
  float acc = b1[t];
  #pragma unroll 8
  for (int k = 0; k < HD; ++k) acc += row[k] * w1[(size_t)k * 64 + t];
  float v = fmaxf(acc, 0.f) * w2[t];
  #pragma unroll
  for (int off = 32; off > 0; off >>= 1) v += __shfl_down(v, off);
  if (t == 0) out[g] = v + b2[0];
}

extern "C" void kernel_launch(void* const* d_in, const int* in_sizes, int n_in,
                              void* d_out, int out_size, void* d_ws, size_t ws_size,
                              hipStream_t stream) {
  const float* x      = (const float*)d_in[0];
  const float* ea     = (const float*)d_in[1];
  const int*   eidx   = (const int*)d_in[2];
  const int*   batch  = (const int*)d_in[3];
  const float* w1_0   = (const float*)d_in[4];
  const float* b1_0   = (const float*)d_in[5];
  const float* w2_0   = (const float*)d_in[6];
  const float* b2_0   = (const float*)d_in[7];
  const float* root_0 = (const float*)d_in[8];
  const float* bias_0 = (const float*)d_in[9];
  const float* bn_g0  = (const float*)d_in[10];
  const float* bn_b0  = (const float*)d_in[11];
  const float* bn_m0  = (const float*)d_in[12];
  const float* bn_v0  = (const float*)d_in[13];
  const float* w1_s   = (const float*)d_in[14];
  const float* b1_s   = (const float*)d_in[15];
  const float* w2_s   = (const float*)d_in[16];
  const float* b2_s   = (const float*)d_in[17];
  const float* root_s = (const float*)d_in[18];
  const float* bias_s = (const float*)d_in[19];
  const float* bn_gs  = (const float*)d_in[20];
  const float* bn_bs  = (const float*)d_in[21];
  const float* bn_ms  = (const float*)d_in[22];
  const float* bn_vs  = (const float*)d_in[23];
  const float* lin1_w = (const float*)d_in[24];
  const float* lin1_b = (const float*)d_in[25];
  const float* lin2_w = (const float*)d_in[26];
  const float* lin2_b = (const float*)d_in[27];
  float* out = (float*)d_out;

  char* w = (char*)d_ws;
  size_t off = 0;
  auto alloc = [&](size_t bytes) { void* p = w + off; off = (off + bytes + 255) & ~(size_t)255; return p; };
  int*   counts = (int*)alloc(NN * 4);
  int*   rowptr = (int*)alloc((NN + 4) * 4);
  int*   elist  = (int*)alloc(NE * 4);
  int*   gstart = (int*)alloc((NG + 4) * 4);
  float* h_edge = (float*)alloc((size_t)5 * NE * HD * 4);
  float* hnA    = (float*)alloc((size_t)NN * HD * 4);
  float* hnB    = (float*)alloc((size_t)NN * HD * 4);
  float* aggr   = (float*)alloc((size_t)NN * HD * 4);
  float* msgp   = (float*)alloc((size_t)SK * NE * HD * 4);
  float* pooled = (float*)alloc((size_t)NG * HD * 4);

  const int* src = eidx;
  const int* dstp = eidx + NE;

  hipMemsetAsync(counts, 0, NN * 4, stream);
  k_count<<<dim3((NE + 255) / 256), dim3(256), 0, stream>>>(dstp, counts);
  k_scan<<<1, 1024, 0, stream>>>(counts, rowptr);
  k_fill<<<4, 1024, 0, stream>>>(dstp, rowptr, elist);
  k_gbounds<<<1, 256, 0, stream>>>(batch, gstart);
  k_hall<<<dim3(5 * NE * HD / 256), 256, 0, stream>>>(ea, w1_0, b1_0, w1_s, b1_s, h_edge);

  // layer 0 (in = 11, padded to 16)
  k_msg<16, 11><<<dim3(NE / BM, HD / BN, SK), 256, 0, stream>>>(x, h_edge, w2_0, b2_0, src, msgp);
  k_aggr<<<NN, HD, 0, stream>>>(msgp, rowptr, elist, aggr);
  k_update<11><<<NN, HD, 0, stream>>>(aggr, x, root_0, bias_0, bn_g0, bn_b0, bn_m0, bn_v0,
                                      nullptr, hnA);

  float* cur = hnA;
  float* nxt = hnB;
  for (int l = 1; l <= 4; ++l) {
    const float* w2l = w2_s + (size_t)(l - 1) * HD * HD * HD;
    const float* b2l = b2_s + (size_t)(l - 1) * HD * HD;
    k_msg<128, 128><<<dim3(NE / BM, HD / BN, SK), 256, 0, stream>>>(
        cur, h_edge + (size_t)l * NE * HD, w2l, b2l, src, msgp);
    k_aggr<<<NN, HD, 0, stream>>>(msgp, rowptr, elist, aggr);
    k_update<128><<<NN, HD, 0, stream>>>(aggr, cur, root_s + (size_t)(l - 1) * HD * HD,
                                         bias_s + (size_t)(l - 1) * HD,
                                         bn_gs + (size_t)(l - 1) * HD, bn_bs + (size_t)(l - 1) * HD,
                                         bn_ms + (size_t)(l - 1) * HD, bn_vs + (size_t)(l - 1) * HD,
                                         cur, nxt);
    float* tmp = cur; cur = nxt; nxt = tmp;
  }

  k_pool<<<NG, HD, 0, stream>>>(cur, gstart, pooled);
  k_readout<<<NG, 64, 0, stream>>>(pooled, lin1_w, lin1_b, lin2_w, lin2_b, out);
}

// Round 2
// 388.569 us; speedup vs baseline: 3.9777x; 3.9777x over previous
//
#include <hip/hip_runtime.h>
#include <cstdint>
#include <cstddef>

#define NN 2048   // nodes
#define NE 4096   // edges
#define NG 128    // graphs
#define HD 128    // hidden
#define SKM 16    // split-K blocks for layers 1-4 (516 chunks: 4x33 + 12x32)
#define SK0 5     // split-K blocks for layer 0 (65 chunks: 5x13)

typedef unsigned short u16;
typedef __attribute__((ext_vector_type(8))) short s16x8;
typedef __attribute__((ext_vector_type(4))) float f32x4;

__device__ inline float b2f(u16 u) {
  return __builtin_bit_cast(float, (unsigned int)u << 16);
}
__device__ inline u16 f2b(float f) {
  __bf16 b = (__bf16)f;
  return __builtin_bit_cast(unsigned short, b);
}

#define GLOAD_LDS16(gptr, lptr)                                                          \
  __builtin_amdgcn_global_load_lds((const __attribute__((address_space(1))) unsigned int*)(gptr), \
                                   (__attribute__((address_space(3))) unsigned int*)(lptr), 16, 0, 0)

// ---------------- CSR build (deterministic) ----------------
__global__ void k_count(const int* __restrict__ dst, int* __restrict__ counts) {
  int e = blockIdx.x * 256 + threadIdx.x;
  if (e < NE) atomicAdd(&counts[dst[e]], 1);
}

__global__ __launch_bounds__(1024) void k_scan(const int* __restrict__ counts,
                                               int* __restrict__ rowptr) {
  __shared__ int s[NN];
  int t = threadIdx.x;
  s[t] = counts[t];
  s[t + 1024] = counts[t + 1024];
  __syncthreads();
  for (int d = 1; d < NN; d <<= 1) {
    int a0 = s[t], a1 = s[t + 1024];
    int v0 = (t >= d) ? s[t - d] : 0;
    int v1 = (t + 1024 >= d) ? s[t + 1024 - d] : 0;
    __syncthreads();
    s[t] = a0 + v0;
    s[t + 1024] = a1 + v1;
    __syncthreads();
  }
  rowptr[t + 1] = s[t];
  rowptr[t + 1025] = s[t + 1024];
  if (t == 0) rowptr[0] = 0;
}

__global__ __launch_bounds__(1024) void k_fill(const int* __restrict__ dst,
                                               const int* __restrict__ rowptr,
                                               int* __restrict__ elist) {
  __shared__ int sd[NE];
  int t = threadIdx.x;
  for (int i = t; i < NE; i += 1024) sd[i] = dst[i];
  __syncthreads();
  int e = blockIdx.x * 1024 + t;
  int dv = sd[e];
  int rank = 0;
  for (int j = 0; j < e; ++j) rank += (sd[j] == dv) ? 1 : 0;
  elist[rowptr[dv] + rank] = e;   // stable order -> deterministic float sums
}

__global__ void k_gbounds(const int* __restrict__ batch, int* __restrict__ gstart) {
  int g = threadIdx.x;
  if (g > NG) return;
  int lo = 0, hi = NN;
  while (lo < hi) { int mid = (lo + hi) >> 1; if (batch[mid] < g) lo = mid + 1; else hi = mid; }
  gstart[g] = lo;
}

// ---------------- edge MLP h for all 5 layers (bf16 out) ----------------
__global__ void k_hall(const float* __restrict__ ea,
                       const float* __restrict__ w1_0, const float* __restrict__ b1_0,
                       const float* __restrict__ w1_s, const float* __restrict__ b1_s,
                       u16* __restrict__ hb) {
  int idx = blockIdx.x * 256 + threadIdx.x;   // l*2^19 + e*128 + c
  int c = idx & (HD - 1);
  int e = (idx >> 7) & (NE - 1);
  int l = idx >> 19;
  const float* w1 = (l == 0) ? w1_0 : (w1_s + (size_t)(l - 1) * 4 * HD);
  const float* b1 = (l == 0) ? b1_0 : (b1_s + (size_t)(l - 1) * HD);
  float4 a = *(const float4*)(ea + (size_t)e * 4);
  float v = b1[c] + a.x * w1[c] + a.y * w1[HD + c] + a.z * w1[2 * HD + c] + a.w * w1[3 * HD + c];
  hb[idx] = f2b(fmaxf(v, 0.f));
}

// ---------------- weight prep ----------------
// layers 1-4: w2T[l][o][kappa] bf16, kappa = k*128+i (<16384: w2 flat), >=16384: b2 rows
__global__ __launch_bounds__(256) void k_w2t(const float* __restrict__ w2s,
                                             const float* __restrict__ b2s,
                                             u16* __restrict__ w2T) {
  int l = blockIdx.z;
  const float* w2 = w2s + (size_t)l * 16384 * 128;
  const float* b2 = b2s + (size_t)l * 128 * 128;
  u16* out = w2T + (size_t)l * 128 * 16512;
  __shared__ float s[64][65];
  int k0 = blockIdx.x * 64, o0 = blockIdx.y * 64;
  int t = threadIdx.x;
  int r = t >> 4, c = (t & 15) * 4;
#pragma unroll
  for (int it = 0; it < 4; ++it) {
    int kk = k0 + r + it * 16;
    const float* srcp = (kk < 16384) ? (w2 + (size_t)kk * 128 + o0 + c)
                                     : (b2 + (size_t)(kk - 16384) * 128 + o0 + c);
    *(float4*)&s[r + it * 16][c] = *(const float4*)srcp;
  }
  __syncthreads();
#pragma unroll
  for (int it = 0; it < 4; ++it) {
    int o = o0 + r + it * 16;
    u16 pk[4];
#pragma unroll
    for (int j = 0; j < 4; ++j) pk[j] = f2b(s[c + j][r + it * 16]);
    *(unsigned long long*)(out + (size_t)o * 16512 + k0 + c) = *(unsigned long long*)pk;
  }
}

// layer 0: w2T0[o][kappa] bf16, kappa = 16*k + i (i<11 valid, k=128 bias, rest 0), KT0=2080
__global__ void k_w2t0(const float* __restrict__ w2_0, const float* __restrict__ b2_0,
                       u16* __restrict__ w2T0) {
  int o = blockIdx.x, t = threadIdx.x;
  for (int kap = t; kap < 2080; kap += 256) {
    int k = kap >> 4, i = kap & 15;
    float v = 0.f;
    if (i < 11) {
      if (k < 128) v = w2_0[(size_t)k * 1408 + i * 128 + o];
      else if (k == 128) v = b2_0[i * 128 + o];
    }
    w2T0[(size_t)o * 2080 + kap] = f2b(v);
  }
}

// pad x [2048][11] f32 -> [2048][16] bf16
__global__ void k_padx(const float* __restrict__ x, u16* __restrict__ xb) {
  int idx = blockIdx.x * 256 + threadIdx.x;
  int n = idx >> 4, i = idx & 15;
  xb[idx] = f2b(i < 11 ? x[(size_t)n * 11 + i] : 0.f);
}

// ---------------- MFMA message GEMM ----------------
// msg[e][o] = sum_kappa Z[e][kappa] * w2T[o][kappa]
//   L14: kappa = k*128+i, K=16512 (h row 128 == 1.0 folds bias)
//   L0 : kappa = k*16 +i, K=2080
__device__ inline s16x8 mulpack(s16x8 x, float h) {
  s16x8 r;
#pragma unroll
  for (int j = 0; j < 8; ++j) {
    float xf = b2f((u16)x[j]);
    r[j] = __builtin_bit_cast(short, (__bf16)(xf * h));
  }
  return r;
}

template <bool L0>
__global__ __launch_bounds__(256, 2) void k_mma(
    const u16* __restrict__ xsb,    // L0: [NN][16] else [NN][128] bf16
    const u16* __restrict__ hb,     // [NE][128] bf16 (this layer)
    const u16* __restrict__ w2T,    // [128][KT] bf16
    const int* __restrict__ src,
    u16* __restrict__ msgp) {       // [SK][NE][128] bf16 partials
  constexpr int KT = L0 ? 2080 : 16512;
  __shared__ u16 hT[130][128];      // transposed h (+1.0 row, +0 row)
  __shared__ u16 Bs[2][128][32];    // double-buffered B slab (8KB each)

  const int tid = threadIdx.x;
  const int e0 = blockIdx.x * 128;
  const int w = tid >> 6, l = tid & 63, l16 = l & 15, g = l >> 4;
  const int wm0 = w * 32;

  int cb, ncb;
  if constexpr (L0) {
    cb = blockIdx.y * 13; ncb = 13;
  } else {
    int sk = blockIdx.y;
    if (sk < 4) { cb = sk * 33; ncb = 33; }
    else        { cb = 132 + (sk - 4) * 32; ncb = 32; }
  }

  // ---- stage hT (transpose h rows of this block's 128 edges) ----
  {
    int m = tid >> 4;
    int k0 = (tid & 15) * 8;
#pragma unroll
    for (int it = 0; it < 8; ++it, m += 16) {
      s16x8 v = *(const s16x8*)(hb + (size_t)(e0 + m) * 128 + k0);
#pragma unroll
      for (int j = 0; j < 8; ++j) hT[k0 + j][m] = (u16)v[j];
    }
    if (tid < 128) { hT[128][tid] = 0x3F80; hT[129][tid] = 0; }  // 1.0, 0.0
  }

  // ---- x_src rows into registers ----
  const int eA = e0 + wm0 + l16, eB = eA + 16;
  const int nA = src[eA], nB = src[eB];
  s16x8 xr0[L0 ? 1 : 4], xr1[L0 ? 1 : 4];
  if constexpr (L0) {
    xr0[0] = *(const s16x8*)(xsb + (size_t)nA * 16 + (g & 1) * 8);
    xr1[0] = *(const s16x8*)(xsb + (size_t)nB * 16 + (g & 1) * 8);
  } else {
#pragma unroll
    for (int q = 0; q < 4; ++q) {
      xr0[q] = *(const s16x8*)(xsb + (size_t)nA * 128 + g * 8 + q * 32);
      xr1[q] = *(const s16x8*)(xsb + (size_t)nB * 128 + g * 8 + q * 32);
    }
  }

  // ---- B staging helper: slab rows [0,128) x 32 kappa, wave w does rows [w*32, w*32+32) ----
  auto stageB = [&](int b, int c) {
    const int kap0 = c * 32;
    const int row = w * 32 + (l >> 2);
    const u16* gp = w2T + (size_t)row * KT + kap0 + (l & 3) * 8;
    GLOAD_LDS16(gp, &Bs[b][w * 32][0]);
    const u16* gp2 = gp + (size_t)16 * KT;
    GLOAD_LDS16(gp2, &Bs[b][w * 32 + 16][0]);
  };

  stageB(0, cb);
  __syncthreads();

  f32x4 acc[2][8] = {};
  for (int cc = 0; cc < ncb; ++cc) {
    const int c = cb + cc, buf = cc & 1;
    if (cc + 1 < ncb) stageB(buf ^ 1, c + 1);

    float h0, h1;
    if constexpr (L0) {
      int k = 2 * c + (g >> 1);
      h0 = b2f(hT[k][wm0 + l16]);
      h1 = b2f(hT[k][wm0 + 16 + l16]);
    } else {
      int k = c >> 2;
      h0 = b2f(hT[k][wm0 + l16]);
      h1 = b2f(hT[k][wm0 + 16 + l16]);
    }

    s16x8 xv0, xv1;
    if constexpr (L0) {
      xv0 = xr0[0]; xv1 = xr1[0];
    } else {
      switch (c & 3) {   // static indexing: keep xr in registers (no scratch)
        case 0: xv0 = xr0[0]; xv1 = xr1[0]; break;
        case 1: xv0 = xr0[1]; xv1 = xr1[1]; break;
        case 2: xv0 = xr0[2]; xv1 = xr1[2]; break;
        default: xv0 = xr0[3]; xv1 = xr1[3]; break;
      }
    }
    s16x8 a0 = mulpack(xv0, h0);
    s16x8 a1 = mulpack(xv1, h1);

#pragma unroll
    for (int nt = 0; nt < 8; ++nt) {
      s16x8 bfr = *(const s16x8*)&Bs[buf][nt * 16 + l16][g * 8];
      acc[0][nt] = __builtin_amdgcn_mfma_f32_16x16x32_bf16(a0, bfr, acc[0][nt], 0, 0, 0);
      acc[1][nt] = __builtin_amdgcn_mfma_f32_16x16x32_bf16(a1, bfr, acc[1][nt], 0, 0, 0);
    }
    __syncthreads();   // drains vmcnt for next buf + guards buf reuse
  }

  // ---- epilogue: D row = 4g + r (m89/m91-verified), col = l16 ----
  u16* mp = msgp + ((size_t)blockIdx.y * NE + e0) * 128;
#pragma unroll
  for (int mt = 0; mt < 2; ++mt)
#pragma unroll
    for (int nt = 0; nt < 8; ++nt)
#pragma unroll
      for (int r = 0; r < 4; ++r) {
        int row = wm0 + mt * 16 + 4 * g + r;
        mp[(size_t)row * 128 + nt * 16 + l16] = f2b(acc[mt][nt][r]);
      }
}

// ---------------- split-K reduce + scatter-mean ----------------
template <int NSK>
__global__ void k_aggr(const u16* __restrict__ msgp, const int* __restrict__ rowptr,
                       const int* __restrict__ elist, float* __restrict__ aggr) {
  int n = blockIdx.x, t = threadIdx.x;  // 128 threads
  int beg = rowptr[n], end = rowptr[n + 1];
  float v = 0.f;
  for (int j = beg; j < end; ++j) {
    int e = elist[j];
#pragma unroll
    for (int s = 0; s < NSK; ++s) v += b2f(msgp[((size_t)s * NE + e) * HD + t]);
  }
  aggr[(size_t)n * HD + t] = v / fmaxf((float)(end - beg), 1.f);
}

// ---------------- aggr + x@root + bias -> BN -> ReLU (+residual) ----------------
template <int INR>
__global__ void k_update(const float* __restrict__ aggr, const float* __restrict__ xin,
                         const float* __restrict__ root, const float* __restrict__ bias,
                         const float* __restrict__ bg, const float* __restrict__ bb,
                         const float* __restrict__ bm, const float* __restrict__ bv,
                         const float* __restrict__ h_prev, float* __restrict__ h_out,
                         u16* __restrict__ h_out_bf) {
  int n = blockIdx.x, t = threadIdx.x;  // 128 threads
  __shared__ float xr[INR];
  if (t < INR) xr[t] = xin[(size_t)n * INR + t];
  __syncthreads();
  float acc = aggr[(size_t)n * HD + t] + bias[t];
#pragma unroll 8
  for (int k = 0; k < INR; ++k) acc += xr[k] * root[(size_t)k * HD + t];
  float bn = (acc - bm[t]) * rsqrtf(bv[t] + 1e-5f) * bg[t] + bb[t];
  float r = fmaxf(bn, 0.f);
  float val = h_prev ? (h_prev[(size_t)n * HD + t] + r) : r;
  h_out[(size_t)n * HD + t] = val;
  h_out_bf[(size_t)n * HD + t] = f2b(val);
}

// ---------------- global mean pool ----------------
__global__ void k_pool(const float* __restrict__ h, const int* __restrict__ gstart,
                       float* __restrict__ pooled) {
  int g = blockIdx.x, t = threadIdx.x;  // 128 threads
  int beg = gstart[g], end = gstart[g + 1];
  float v = 0.f;
  for (int n = beg; n < end; ++n) v += h[(size_t)n * HD + t];
  pooled[(size_t)g * HD + t] = v / fmaxf((float)(end - beg), 1.f);
}

// ---------------- readout MLP ----------------
__global__ void k_readout(const float* __restrict__ pooled,
                          const float* __restrict__ w1, const float* __restrict__ b1,
                          const float* __restrict__ w2, const float* __restrict__ b2,
                          float* __restrict__ out) {
  int g = blockIdx.x, t = threadIdx.x;  // 64 threads
  __shared__ float row[HD];
  row[t] = pooled[(size_t)g * HD + t];
  row[t + 64] = pooled[(size_t)g * HD + t + 64];
  __syncthreads();
  float acc = b1[t];
#pragma unroll 8
  for (int k = 0; k < HD; ++k) acc += row[k] * w1[(size_t)k * 64 + t];
  float v = fmaxf(acc, 0.f) * w2[t];
#pragma unroll
  for (int off = 32; off > 0; off >>= 1) v += __shfl_down(v, off);
  if (t == 0) out[g] = v + b2[0];
}

extern "C" void kernel_launch(void* const* d_in, const int* in_sizes, int n_in,
                              void* d_out, int out_size, void* d_ws, size_t ws_size,
                              hipStream_t stream) {
  const float* x      = (const float*)d_in[0];
  const float* ea     = (const float*)d_in[1];
  const int*   eidx   = (const int*)d_in[2];
  const int*   batch  = (const int*)d_in[3];
  const float* w1_0   = (const float*)d_in[4];
  const float* b1_0   = (const float*)d_in[5];
  const float* w2_0   = (const float*)d_in[6];
  const float* b2_0   = (const float*)d_in[7];
  const float* root_0 = (const float*)d_in[8];
  const float* bias_0 = (const float*)d_in[9];
  const float* bn_g0  = (const float*)d_in[10];
  const float* bn_b0  = (const float*)d_in[11];
  const float* bn_m0  = (const float*)d_in[12];
  const float* bn_v0  = (const float*)d_in[13];
  const float* w1_s   = (const float*)d_in[14];
  const float* b1_s   = (const float*)d_in[15];
  const float* w2_s   = (const float*)d_in[16];
  const float* b2_s   = (const float*)d_in[17];
  const float* root_s = (const float*)d_in[18];
  const float* bias_s = (const float*)d_in[19];
  const float* bn_gs  = (const float*)d_in[20];
  const float* bn_bs  = (const float*)d_in[21];
  const float* bn_ms  = (const float*)d_in[22];
  const float* bn_vs  = (const float*)d_in[23];
  const float* lin1_w = (const float*)d_in[24];
  const float* lin1_b = (const float*)d_in[25];
  const float* lin2_w = (const float*)d_in[26];
  const float* lin2_b = (const float*)d_in[27];
  float* out = (float*)d_out;

  char* wsb = (char*)d_ws;
  size_t off = 0;
  auto alloc = [&](size_t bytes) { void* p = wsb + off; off = (off + bytes + 255) & ~(size_t)255; return p; };
  int*   counts = (int*)alloc(NN * 4);
  int*   rowptr = (int*)alloc((NN + 4) * 4);
  int*   elist  = (int*)alloc(NE * 4);
  int*   gstart = (int*)alloc((NG + 4) * 4);
  u16*   hbf    = (u16*)alloc((size_t)5 * NE * HD * 2);
  u16*   xbf0   = (u16*)alloc((size_t)NN * 16 * 2);
  u16*   w2T0   = (u16*)alloc((size_t)128 * 2080 * 2);
  u16*   w2T    = (u16*)alloc((size_t)4 * 128 * 16512 * 2);
  float* hnA    = (float*)alloc((size_t)NN * HD * 4);
  float* hnB    = (float*)alloc((size_t)NN * HD * 4);
  u16*   hnAb   = (u16*)alloc((size_t)NN * HD * 2);
  u16*   hnBb   = (u16*)alloc((size_t)NN * HD * 2);
  float* aggr   = (float*)alloc((size_t)NN * HD * 4);
  u16*   msgp   = (u16*)alloc((size_t)SKM * NE * HD * 2);
  float* pooled = (float*)alloc((size_t)NG * HD * 4);

  const int* src = eidx;
  const int* dstp = eidx + NE;

  hipMemsetAsync(counts, 0, NN * 4, stream);
  k_count<<<dim3((NE + 255) / 256), dim3(256), 0, stream>>>(dstp, counts);
  k_scan<<<1, 1024, 0, stream>>>(counts, rowptr);
  k_fill<<<4, 1024, 0, stream>>>(dstp, rowptr, elist);
  k_gbounds<<<1, 256, 0, stream>>>(batch, gstart);
  k_hall<<<dim3(5 * NE * HD / 256), 256, 0, stream>>>(ea, w1_0, b1_0, w1_s, b1_s, hbf);
  k_padx<<<dim3(NN * 16 / 256), 256, 0, stream>>>(x, xbf0);
  k_w2t0<<<dim3(128), 256, 0, stream>>>(w2_0, b2_0, w2T0);
  k_w2t<<<dim3(16512 / 64, 2, 4), 256, 0, stream>>>(w2_s, b2_s, w2T);

  // layer 0
  k_mma<true><<<dim3(NE / 128, SK0), 256, 0, stream>>>(xbf0, hbf, w2T0, src, msgp);
  k_aggr<SK0><<<NN, HD, 0, stream>>>(msgp, rowptr, elist, aggr);
  k_update<11><<<NN, HD, 0, stream>>>(aggr, x, root_0, bias_0, bn_g0, bn_b0, bn_m0, bn_v0,
                                      nullptr, hnA, hnAb);

  float* cur = hnA;  u16* curb = hnAb;
  float* nxt = hnB;  u16* nxtb = hnBb;
  for (int l = 1; l <= 4; ++l) {
    const u16* w2Tl = w2T + (size_t)(l - 1) * 128 * 16512;
    k_mma<false><<<dim3(NE / 128, SKM), 256, 0, stream>>>(
        curb, hbf + (size_t)l * NE * HD, w2Tl, src, msgp);
    k_aggr<SKM><<<NN, HD, 0, stream>>>(msgp, rowptr, elist, aggr);
    k_update<128><<<NN, HD, 0, stream>>>(aggr, cur, root_s + (size_t)(l - 1) * HD * HD,
                                         bias_s + (size_t)(l - 1) * HD,
                                         bn_gs + (size_t)(l - 1) * HD, bn_bs + (size_t)(l - 1) * HD,
                                         bn_ms + (size_t)(l - 1) * HD, bn_vs + (size_t)(l - 1) * HD,
                                         cur, nxt, nxtb);
    float* tf = cur; cur = nxt; nxt = tf;
    u16* tb = curb; curb = nxtb; nxtb = tb;
  }

  k_pool<<<NG, HD, 0, stream>>>(cur, gstart, pooled);
  k_readout<<<NG, 64, 0, stream>>>(pooled, lin1_w, lin1_b, lin2_w, lin2_b, out);
}

// Round 3
// 275.264 us; speedup vs baseline: 5.6150x; 1.4116x over previous
//
#include <hip/hip_runtime.h>
#include <cstdint>
#include <cstddef>

#define NN 2048   // nodes
#define NE 4096   // edges
#define NG 128    // graphs
#define HD 128    // hidden
#define SKM 16    // split-K blocks for layers 1-4 (516 chunks: 4x33 + 12x32)
#define SK0 5     // split-K blocks for layer 0 (65 chunks: 5x13)
#define NCH 64    // CSR sort chunks
#define CHE 64    // edges per chunk

typedef unsigned short u16;
typedef __attribute__((ext_vector_type(8))) short s16x8;
typedef __attribute__((ext_vector_type(4))) float f32x4;

__device__ inline float b2f(u16 u) {
  return __builtin_bit_cast(float, (unsigned int)u << 16);
}
__device__ inline u16 f2b(float f) {
  __bf16 b = (__bf16)f;
  return __builtin_bit_cast(unsigned short, b);
}

#define GLOAD_LDS16(gptr, lptr)                                                          \
  __builtin_amdgcn_global_load_lds((const __attribute__((address_space(1))) unsigned int*)(gptr), \
                                   (__attribute__((address_space(3))) unsigned int*)(lptr), 16, 0, 0)

// ---------------- CSR build (deterministic, chunked stable counting sort) ----------------
__global__ void k_count(const int* __restrict__ dst, int* __restrict__ counts,
                        int* __restrict__ hist) {
  int e = blockIdx.x * 256 + threadIdx.x;
  if (e < NE) {
    int d = dst[e];
    atomicAdd(&counts[d], 1);
    atomicAdd(&hist[(e >> 6) * NN + d], 1);   // per-chunk histogram (int: deterministic)
  }
}

__global__ __launch_bounds__(1024) void k_scan(const int* __restrict__ counts,
                                               int* __restrict__ rowptr) {
  __shared__ int s[NN];
  int t = threadIdx.x;
  s[t] = counts[t];
  s[t + 1024] = counts[t + 1024];
  __syncthreads();
  for (int d = 1; d < NN; d <<= 1) {
    int a0 = s[t], a1 = s[t + 1024];
    int v0 = (t >= d) ? s[t - d] : 0;
    int v1 = (t + 1024 >= d) ? s[t + 1024 - d] : 0;
    __syncthreads();
    s[t] = a0 + v0;
    s[t + 1024] = a1 + v1;
    __syncthreads();
  }
  rowptr[t + 1] = s[t];
  rowptr[t + 1025] = s[t + 1024];
  if (t == 0) rowptr[0] = 0;
}

// per-node running prefix across chunks: chunkoff[c][n] = rowptr[n] + sum_{c'<c} hist[c'][n]
__global__ void k_chunkscan(const int* __restrict__ hist, const int* __restrict__ rowptr,
                            int* __restrict__ chunkoff) {
  int n = blockIdx.x * 256 + threadIdx.x;
  int running = rowptr[n];
#pragma unroll 8
  for (int c = 0; c < NCH; ++c) {
    chunkoff[c * NN + n] = running;
    running += hist[c * NN + n];
  }
}

// one 64-thread block per chunk; stable local rank via <=63-entry LDS scan
__global__ __launch_bounds__(64) void k_fill2(const int* __restrict__ dst,
                                              const int* __restrict__ chunkoff,
                                              int* __restrict__ elist) {
  __shared__ int sd[CHE];
  int c = blockIdx.x, t = threadIdx.x;
  int e = c * CHE + t;
  int dv = dst[e];
  sd[t] = dv;
  __syncthreads();
  int lrank = 0;
  for (int j = 0; j < t; ++j) lrank += (sd[j] == dv) ? 1 : 0;
  elist[chunkoff[c * NN + dv] + lrank] = e;   // stable order -> deterministic float sums
}

__global__ void k_gbounds(const int* __restrict__ batch, int* __restrict__ gstart) {
  int g = threadIdx.x;
  if (g > NG) return;
  int lo = 0, hi = NN;
  while (lo < hi) { int mid = (lo + hi) >> 1; if (batch[mid] < g) lo = mid + 1; else hi = mid; }
  gstart[g] = lo;
}

// ---------------- edge MLP h for all 5 layers (bf16 out) ----------------
__global__ void k_hall(const float* __restrict__ ea,
                       const float* __restrict__ w1_0, const float* __restrict__ b1_0,
                       const float* __restrict__ w1_s, const float* __restrict__ b1_s,
                       u16* __restrict__ hb) {
  int idx = blockIdx.x * 256 + threadIdx.x;   // l*2^19 + e*128 + c
  int c = idx & (HD - 1);
  int e = (idx >> 7) & (NE - 1);
  int l = idx >> 19;
  const float* w1 = (l == 0) ? w1_0 : (w1_s + (size_t)(l - 1) * 4 * HD);
  const float* b1 = (l == 0) ? b1_0 : (b1_s + (size_t)(l - 1) * HD);
  float4 a = *(const float4*)(ea + (size_t)e * 4);
  float v = b1[c] + a.x * w1[c] + a.y * w1[HD + c] + a.z * w1[2 * HD + c] + a.w * w1[3 * HD + c];
  hb[idx] = f2b(fmaxf(v, 0.f));
}

// ---------------- weight prep ----------------
__global__ __launch_bounds__(256) void k_w2t(const float* __restrict__ w2s,
                                             const float* __restrict__ b2s,
                                             u16* __restrict__ w2T) {
  int l = blockIdx.z;
  const float* w2 = w2s + (size_t)l * 16384 * 128;
  const float* b2 = b2s + (size_t)l * 128 * 128;
  u16* out = w2T + (size_t)l * 128 * 16512;
  __shared__ float s[64][65];
  int k0 = blockIdx.x * 64, o0 = blockIdx.y * 64;
  int t = threadIdx.x;
  int r = t >> 4, c = (t & 15) * 4;
#pragma unroll
  for (int it = 0; it < 4; ++it) {
    int kk = k0 + r + it * 16;
    const float* srcp = (kk < 16384) ? (w2 + (size_t)kk * 128 + o0 + c)
                                     : (b2 + (size_t)(kk - 16384) * 128 + o0 + c);
    *(float4*)&s[r + it * 16][c] = *(const float4*)srcp;
  }
  __syncthreads();
#pragma unroll
  for (int it = 0; it < 4; ++it) {
    int o = o0 + r + it * 16;
    u16 pk[4];
#pragma unroll
    for (int j = 0; j < 4; ++j) pk[j] = f2b(s[c + j][r + it * 16]);
    *(unsigned long long*)(out + (size_t)o * 16512 + k0 + c) = *(unsigned long long*)pk;
  }
}

__global__ void k_w2t0(const float* __restrict__ w2_0, const float* __restrict__ b2_0,
                       u16* __restrict__ w2T0) {
  int o = blockIdx.x, t = threadIdx.x;
  for (int kap = t; kap < 2080; kap += 256) {
    int k = kap >> 4, i = kap & 15;
    float v = 0.f;
    if (i < 11) {
      if (k < 128) v = w2_0[(size_t)k * 1408 + i * 128 + o];
      else if (k == 128) v = b2_0[i * 128 + o];
    }
    w2T0[(size_t)o * 2080 + kap] = f2b(v);
  }
}

__global__ void k_padx(const float* __restrict__ x, u16* __restrict__ xb) {
  int idx = blockIdx.x * 256 + threadIdx.x;
  int n = idx >> 4, i = idx & 15;
  xb[idx] = f2b(i < 11 ? x[(size_t)n * 11 + i] : 0.f);
}

// ---------------- MFMA message GEMM ----------------
__device__ inline s16x8 mulpack(s16x8 x, float h) {
  s16x8 r;
#pragma unroll
  for (int j = 0; j < 8; ++j) {
    float xf = b2f((u16)x[j]);
    r[j] = __builtin_bit_cast(short, (__bf16)(xf * h));
  }
  return r;
}

template <bool L0>
__global__ __launch_bounds__(256, 2) void k_mma(
    const u16* __restrict__ xsb,    // L0: [NN][16] else [NN][128] bf16
    const u16* __restrict__ hb,     // [NE][128] bf16 (this layer)
    const u16* __restrict__ w2T,    // [128][KT] bf16
    const int* __restrict__ src,
    u16* __restrict__ msgp) {       // [SK][NE][128] bf16 partials
  constexpr int KT = L0 ? 2080 : 16512;
  __shared__ u16 hT[130][128];      // transposed h (+1.0 row, +0 row)
  __shared__ u16 Bs[2][128][32];    // double-buffered B slab (8KB each)

  const int tid = threadIdx.x;
  const int e0 = blockIdx.x * 128;
  const int w = tid >> 6, l = tid & 63, l16 = l & 15, g = l >> 4;
  const int wm0 = w * 32;

  int cb, ncb;
  if constexpr (L0) {
    cb = blockIdx.y * 13; ncb = 13;
  } else {
    int sk = blockIdx.y;
    if (sk < 4) { cb = sk * 33; ncb = 33; }
    else        { cb = 132 + (sk - 4) * 32; ncb = 32; }
  }

  // ---- stage hT ----
  {
    int m = tid >> 4;
    int k0 = (tid & 15) * 8;
#pragma unroll
    for (int it = 0; it < 8; ++it, m += 16) {
      s16x8 v = *(const s16x8*)(hb + (size_t)(e0 + m) * 128 + k0);
#pragma unroll
      for (int j = 0; j < 8; ++j) hT[k0 + j][m] = (u16)v[j];
    }
    if (tid < 128) { hT[128][tid] = 0x3F80; hT[129][tid] = 0; }  // 1.0, 0.0
  }

  // ---- x_src rows into registers ----
  const int eA = e0 + wm0 + l16, eB = eA + 16;
  const int nA = src[eA], nB = src[eB];
  s16x8 xr0[L0 ? 1 : 4], xr1[L0 ? 1 : 4];
  if constexpr (L0) {
    xr0[0] = *(const s16x8*)(xsb + (size_t)nA * 16 + (g & 1) * 8);
    xr1[0] = *(const s16x8*)(xsb + (size_t)nB * 16 + (g & 1) * 8);
  } else {
#pragma unroll
    for (int q = 0; q < 4; ++q) {
      xr0[q] = *(const s16x8*)(xsb + (size_t)nA * 128 + g * 8 + q * 32);
      xr1[q] = *(const s16x8*)(xsb + (size_t)nB * 128 + g * 8 + q * 32);
    }
  }

  // ---- B staging ----
  auto stageB = [&](int b, int c) {
    const int kap0 = c * 32;
    const int row = w * 32 + (l >> 2);
    const u16* gp = w2T + (size_t)row * KT + kap0 + (l & 3) * 8;
    GLOAD_LDS16(gp, &Bs[b][w * 32][0]);
    const u16* gp2 = gp + (size_t)16 * KT;
    GLOAD_LDS16(gp2, &Bs[b][w * 32 + 16][0]);
  };

  stageB(0, cb);
  __syncthreads();

  f32x4 acc[2][8] = {};
  for (int cc = 0; cc < ncb; ++cc) {
    const int c = cb + cc, buf = cc & 1;
    if (cc + 1 < ncb) stageB(buf ^ 1, c + 1);

    float h0, h1;
    if constexpr (L0) {
      int k = 2 * c + (g >> 1);
      h0 = b2f(hT[k][wm0 + l16]);
      h1 = b2f(hT[k][wm0 + 16 + l16]);
    } else {
      int k = c >> 2;
      h0 = b2f(hT[k][wm0 + l16]);
      h1 = b2f(hT[k][wm0 + 16 + l16]);
    }

    s16x8 xv0, xv1;
    if constexpr (L0) {
      xv0 = xr0[0]; xv1 = xr1[0];
    } else {
      switch (c & 3) {   // static indexing: keep xr in registers
        case 0: xv0 = xr0[0]; xv1 = xr1[0]; break;
        case 1: xv0 = xr0[1]; xv1 = xr1[1]; break;
        case 2: xv0 = xr0[2]; xv1 = xr1[2]; break;
        default: xv0 = xr0[3]; xv1 = xr1[3]; break;
      }
    }
    s16x8 a0 = mulpack(xv0, h0);
    s16x8 a1 = mulpack(xv1, h1);

#pragma unroll
    for (int nt = 0; nt < 8; ++nt) {
      s16x8 bfr = *(const s16x8*)&Bs[buf][nt * 16 + l16][g * 8];
      acc[0][nt] = __builtin_amdgcn_mfma_f32_16x16x32_bf16(a0, bfr, acc[0][nt], 0, 0, 0);
      acc[1][nt] = __builtin_amdgcn_mfma_f32_16x16x32_bf16(a1, bfr, acc[1][nt], 0, 0, 0);
    }
    __syncthreads();
  }

  // ---- epilogue ----
  u16* mp = msgp + ((size_t)blockIdx.y * NE + e0) * 128;
#pragma unroll
  for (int mt = 0; mt < 2; ++mt)
#pragma unroll
    for (int nt = 0; nt < 8; ++nt)
#pragma unroll
      for (int r = 0; r < 4; ++r) {
        int row = wm0 + mt * 16 + 4 * g + r;
        mp[(size_t)row * 128 + nt * 16 + l16] = f2b(acc[mt][nt][r]);
      }
}

// ---------------- split-K reduce + scatter-mean ----------------
template <int NSK>
__global__ void k_aggr(const u16* __restrict__ msgp, const int* __restrict__ rowptr,
                       const int* __restrict__ elist, float* __restrict__ aggr) {
  int n = blockIdx.x, t = threadIdx.x;  // 128 threads
  int beg = rowptr[n], end = rowptr[n + 1];
  float v = 0.f;
  for (int j = beg; j < end; ++j) {
    int e = elist[j];
#pragma unroll
    for (int s = 0; s < NSK; ++s) v += b2f(msgp[((size_t)s * NE + e) * HD + t]);
  }
  aggr[(size_t)n * HD + t] = v / fmaxf((float)(end - beg), 1.f);
}

// ---------------- aggr + x@root + bias -> BN -> ReLU (+residual) ----------------
template <int INR>
__global__ void k_update(const float* __restrict__ aggr, const float* __restrict__ xin,
                         const float* __restrict__ root, const float* __restrict__ bias,
                         const float* __restrict__ bg, const float* __restrict__ bb,
                         const float* __restrict__ bm, const float* __restrict__ bv,
                         const float* __restrict__ h_prev, float* __restrict__ h_out,
                         u16* __restrict__ h_out_bf) {
  int n = blockIdx.x, t = threadIdx.x;  // 128 threads
  __shared__ float xr[INR];
  if (t < INR) xr[t] = xin[(size_t)n * INR + t];
  __syncthreads();
  float acc = aggr[(size_t)n * HD + t] + bias[t];
#pragma unroll 8
  for (int k = 0; k < INR; ++k) acc += xr[k] * root[(size_t)k * HD + t];
  float bn = (acc - bm[t]) * rsqrtf(bv[t] + 1e-5f) * bg[t] + bb[t];
  float r = fmaxf(bn, 0.f);
  float val = h_prev ? (h_prev[(size_t)n * HD + t] + r) : r;
  h_out[(size_t)n * HD + t] = val;
  h_out_bf[(size_t)n * HD + t] = f2b(val);
}

// ---------------- global mean pool ----------------
__global__ void k_pool(const float* __restrict__ h, const int* __restrict__ gstart,
                       float* __restrict__ pooled) {
  int g = blockIdx.x, t = threadIdx.x;  // 128 threads
  int beg = gstart[g], end = gstart[g + 1];
  float v = 0.f;
  for (int n = beg; n < end; ++n) v += h[(size_t)n * HD + t];
  pooled[(size_t)g * HD + t] = v / fmaxf((float)(end - beg), 1.f);
}

// ---------------- readout MLP ----------------
__global__ void k_readout(const float* __restrict__ pooled,
                          const float* __restrict__ w1, const float* __restrict__ b1,
                          const float* __restrict__ w2, const float* __restrict__ b2,
                          float* __restrict__ out) {
  int g = blockIdx.x, t = threadIdx.x;  // 64 threads
  __shared__ float row[HD];
  row[t] = pooled[(size_t)g * HD + t];
  row[t + 64] = pooled[(size_t)g * HD + t + 64];
  __syncthreads();
  float acc = b1[t];
#pragma unroll 8
  for (int k = 0; k < HD; ++k) acc += row[k] * w1[(size_t)k * 64 + t];
  float v = fmaxf(acc, 0.f) * w2[t];
#pragma unroll
  for (int off = 32; off > 0; off >>= 1) v += __shfl_down(v, off);
  if (t == 0) out[g] = v + b2[0];
}

extern "C" void kernel_launch(void* const* d_in, const int* in_sizes, int n_in,
                              void* d_out, int out_size, void* d_ws, size_t ws_size,
                              hipStream_t stream) {
  const float* x      = (const float*)d_in[0];
  const float* ea     = (const float*)d_in[1];
  const int*   eidx   = (const int*)d_in[2];
  const int*   batch  = (const int*)d_in[3];
  const float* w1_0   = (const float*)d_in[4];
  const float* b1_0   = (const float*)d_in[5];
  const float* w2_0   = (const float*)d_in[6];
  const float* b2_0   = (const float*)d_in[7];
  const float* root_0 = (const float*)d_in[8];
  const float* bias_0 = (const float*)d_in[9];
  const float* bn_g0  = (const float*)d_in[10];
  const float* bn_b0  = (const float*)d_in[11];
  const float* bn_m0  = (const float*)d_in[12];
  const float* bn_v0  = (const float*)d_in[13];
  const float* w1_s   = (const float*)d_in[14];
  const float* b1_s   = (const float*)d_in[15];
  const float* w2_s   = (const float*)d_in[16];
  const float* b2_s   = (const float*)d_in[17];
  const float* root_s = (const float*)d_in[18];
  const float* bias_s = (const float*)d_in[19];
  const float* bn_gs  = (const float*)d_in[20];
  const float* bn_bs  = (const float*)d_in[21];
  const float* bn_ms  = (const float*)d_in[22];
  const float* bn_vs  = (const float*)d_in[23];
  const float* lin1_w = (const float*)d_in[24];
  const float* lin1_b = (const float*)d_in[25];
  const float* lin2_w = (const float*)d_in[26];
  const float* lin2_b = (const float*)d_in[27];
  float* out = (float*)d_out;

  char* wsb = (char*)d_ws;
  size_t off = 0;
  auto alloc = [&](size_t bytes) { void* p = wsb + off; off = (off + bytes + 255) & ~(size_t)255; return p; };
  int*   counts   = (int*)alloc(NN * 4);
  int*   rowptr   = (int*)alloc((NN + 4) * 4);
  int*   elist    = (int*)alloc(NE * 4);
  int*   gstart   = (int*)alloc((NG + 4) * 4);
  int*   hist     = (int*)alloc((size_t)NCH * NN * 4);
  int*   chunkoff = (int*)alloc((size_t)NCH * NN * 4);
  u16*   hbf    = (u16*)alloc((size_t)5 * NE * HD * 2);
  u16*   xbf0   = (u16*)alloc((size_t)NN * 16 * 2);
  u16*   w2T0   = (u16*)alloc((size_t)128 * 2080 * 2);
  u16*   w2T    = (u16*)alloc((size_t)4 * 128 * 16512 * 2);
  float* hnA    = (float*)alloc((size_t)NN * HD * 4);
  float* hnB    = (float*)alloc((size_t)NN * HD * 4);
  u16*   hnAb   = (u16*)alloc((size_t)NN * HD * 2);
  u16*   hnBb   = (u16*)alloc((size_t)NN * HD * 2);
  float* aggr   = (float*)alloc((size_t)NN * HD * 4);
  u16*   msgp   = (u16*)alloc((size_t)SKM * NE * HD * 2);
  float* pooled = (float*)alloc((size_t)NG * HD * 4);

  const int* src = eidx;
  const int* dstp = eidx + NE;

  hipMemsetAsync(counts, 0, NN * 4, stream);
  hipMemsetAsync(hist, 0, (size_t)NCH * NN * 4, stream);
  k_count<<<dim3((NE + 255) / 256), dim3(256), 0, stream>>>(dstp, counts, hist);
  k_scan<<<1, 1024, 0, stream>>>(counts, rowptr);
  k_chunkscan<<<dim3(NN / 256), 256, 0, stream>>>(hist, rowptr, chunkoff);
  k_fill2<<<dim3(NCH), 64, 0, stream>>>(dstp, chunkoff, elist);
  k_gbounds<<<1, 256, 0, stream>>>(batch, gstart);
  k_hall<<<dim3(5 * NE * HD / 256), 256, 0, stream>>>(ea, w1_0, b1_0, w1_s, b1_s, hbf);
  k_padx<<<dim3(NN * 16 / 256), 256, 0, stream>>>(x, xbf0);
  k_w2t0<<<dim3(128), 256, 0, stream>>>(w2_0, b2_0, w2T0);
  k_w2t<<<dim3(16512 / 64, 2, 4), 256, 0, stream>>>(w2_s, b2_s, w2T);

  // layer 0
  k_mma<true><<<dim3(NE / 128, SK0), 256, 0, stream>>>(xbf0, hbf, w2T0, src, msgp);
  k_aggr<SK0><<<NN, HD, 0, stream>>>(msgp, rowptr, elist, aggr);
  k_update<11><<<NN, HD, 0, stream>>>(aggr, x, root_0, bias_0, bn_g0, bn_b0, bn_m0, bn_v0,
                                      nullptr, hnA, hnAb);

  float* cur = hnA;  u16* curb = hnAb;
  float* nxt = hnB;  u16* nxtb = hnBb;
  for (int l = 1; l <= 4; ++l) {
    const u16* w2Tl = w2T + (size_t)(l - 1) * 128 * 16512;
    k_mma<false><<<dim3(NE / 128, SKM), 256, 0, stream>>>(
        curb, hbf + (size_t)l * NE * HD, w2Tl, src, msgp);
    k_aggr<SKM><<<NN, HD, 0, stream>>>(msgp, rowptr, elist, aggr);
    k_update<128><<<NN, HD, 0, stream>>>(aggr, cur, root_s + (size_t)(l - 1) * HD * HD,
                                         bias_s + (size_t)(l - 1) * HD,
                                         bn_gs + (size_t)(l - 1) * HD, bn_bs + (size_t)(l - 1) * HD,
                                         bn_ms + (size_t)(l - 1) * HD, bn_vs + (size_t)(l - 1) * HD,
                                         cur, nxt, nxtb);
    float* tf = cur; cur = nxt; nxt = tf;
    u16* tb = curb; curb = nxtb; nxtb = tb;
  }

  k_pool<<<NG, HD, 0, stream>>>(cur, gstart, pooled);
  k_readout<<<NG, 64, 0, stream>>>(pooled, lin1_w, lin1_b, lin2_w, lin2_b, out);
}

// Round 4
// 255.655 us; speedup vs baseline: 6.0457x; 1.0767x over previous
//
#include <hip/hip_runtime.h>
#include <cstdint>
#include <cstddef>

#define NN 2048   // nodes
#define NE 4096   // edges
#define NG 128    // graphs
#define HD 128    // hidden
#define SKM 16    // split-K blocks layers 1-4 (129 k-cols: 9 + 15x8)
#define SK0 5     // split-K blocks layer 0 (65 c-chunks: 5x13)
#define NCH 64    // CSR sort chunks
#define CHE 64    // edges per chunk

typedef unsigned short u16;
typedef __attribute__((ext_vector_type(8))) _Float16 f16x8;
typedef __attribute__((ext_vector_type(4))) float f32x4;

#define GLOAD_LDS16(gptr, lptr)                                                          \
  __builtin_amdgcn_global_load_lds((const __attribute__((address_space(1))) unsigned int*)(gptr), \
                                   (__attribute__((address_space(3))) unsigned int*)(lptr), 16, 0, 0)

// ---------------- CSR build (deterministic, chunked stable counting sort) ----------------
__global__ void k_count(const int* __restrict__ dst, int* __restrict__ hist) {
  int e = blockIdx.x * 256 + threadIdx.x;
  if (e < NE) atomicAdd(&hist[(e >> 6) * NN + dst[e]], 1);
}

// counts-from-hist + scan -> rowptr + chunkoff + graph bounds, all in one block
__global__ __launch_bounds__(1024) void k_scan2(const int* __restrict__ hist,
                                                int* __restrict__ rowptr,
                                                int* __restrict__ chunkoff,
                                                const int* __restrict__ batch,
                                                int* __restrict__ gstart) {
  __shared__ int s[NN];
  int t = threadIdx.x;
  int c0 = 0, c1 = 0;
  for (int c = 0; c < NCH; ++c) { c0 += hist[c * NN + t]; c1 += hist[c * NN + t + 1024]; }
  s[t] = c0; s[t + 1024] = c1;
  __syncthreads();
  for (int d = 1; d < NN; d <<= 1) {
    int a0 = s[t], a1 = s[t + 1024];
    int v0 = (t >= d) ? s[t - d] : 0;
    int v1 = (t + 1024 >= d) ? s[t + 1024 - d] : 0;
    __syncthreads();
    s[t] = a0 + v0; s[t + 1024] = a1 + v1;
    __syncthreads();
  }
  rowptr[t + 1] = s[t]; rowptr[t + 1025] = s[t + 1024];
  if (t == 0) rowptr[0] = 0;
  int run0 = s[t] - c0, run1 = s[t + 1024] - c1;   // exclusive prefix
  for (int c = 0; c < NCH; ++c) {
    chunkoff[c * NN + t] = run0;        run0 += hist[c * NN + t];
    chunkoff[c * NN + t + 1024] = run1; run1 += hist[c * NN + t + 1024];
  }
  if (t <= NG) {
    int lo = 0, hi = NN;
    while (lo < hi) { int mid = (lo + hi) >> 1; if (batch[mid] < t) lo = mid + 1; else hi = mid; }
    gstart[t] = lo;
  }
}

__global__ __launch_bounds__(64) void k_fill2(const int* __restrict__ dst,
                                              const int* __restrict__ chunkoff,
                                              int* __restrict__ elist) {
  __shared__ int sd[CHE];
  int c = blockIdx.x, t = threadIdx.x;
  int e = c * CHE + t;
  int dv = dst[e];
  sd[t] = dv;
  __syncthreads();
  int lrank = 0;
  for (int j = 0; j < t; ++j) lrank += (sd[j] == dv) ? 1 : 0;
  elist[chunkoff[c * NN + dv] + lrank] = e;   // stable order -> deterministic sums
}

// ---------------- edge MLP h (5 layers, f16) + x pad to [2048][16] f16 ----------------
__global__ void k_hallpad(const float* __restrict__ ea,
                          const float* __restrict__ w1_0, const float* __restrict__ b1_0,
                          const float* __restrict__ w1_s, const float* __restrict__ b1_s,
                          const float* __restrict__ x,
                          _Float16* __restrict__ hb, _Float16* __restrict__ x16) {
  int bid = blockIdx.x;
  if (bid < 10240) {
    int idx = bid * 256 + threadIdx.x;   // l*2^19 + e*128 + c
    int c = idx & (HD - 1);
    int e = (idx >> 7) & (NE - 1);
    int l = idx >> 19;
    const float* w1 = (l == 0) ? w1_0 : (w1_s + (size_t)(l - 1) * 4 * HD);
    const float* b1 = (l == 0) ? b1_0 : (b1_s + (size_t)(l - 1) * HD);
    float4 a = *(const float4*)(ea + (size_t)e * 4);
    float v = b1[c] + a.x * w1[c] + a.y * w1[HD + c] + a.z * w1[2 * HD + c] + a.w * w1[3 * HD + c];
    hb[idx] = (_Float16)fmaxf(v, 0.f);
  } else {
    int idx = (bid - 10240) * 256 + threadIdx.x;   // 2048*16
    int n = idx >> 4, i = idx & 15;
    x16[idx] = (_Float16)(i < 11 ? x[(size_t)n * 11 + i] : 0.f);
  }
}

// ---------------- weight prep (f16) ----------------
// layers 1-4: w2T[l][o][kappa], kappa=k*128+i (<16384 from w2 flat; >=16384 b2 rows)
__global__ __launch_bounds__(256) void k_w2t(const float* __restrict__ w2s,
                                             const float* __restrict__ b2s,
                                             _Float16* __restrict__ w2T) {
  int l = blockIdx.z;
  const float* w2 = w2s + (size_t)l * 16384 * 128;
  const float* b2 = b2s + (size_t)l * 128 * 128;
  _Float16* out = w2T + (size_t)l * 128 * 16512;
  __shared__ float s[64][65];
  int k0 = blockIdx.x * 64, o0 = blockIdx.y * 64;
  int t = threadIdx.x;
  int r = t >> 4, c = (t & 15) * 4;
#pragma unroll
  for (int it = 0; it < 4; ++it) {
    int kk = k0 + r + it * 16;
    const float* srcp = (kk < 16384) ? (w2 + (size_t)kk * 128 + o0 + c)
                                     : (b2 + (size_t)(kk - 16384) * 128 + o0 + c);
    *(float4*)&s[r + it * 16][c] = *(const float4*)srcp;
  }
  __syncthreads();
#pragma unroll
  for (int it = 0; it < 4; ++it) {
    int o = o0 + r + it * 16;
    _Float16 pk[4];
#pragma unroll
    for (int j = 0; j < 4; ++j) pk[j] = (_Float16)s[c + j][r + it * 16];
    *(unsigned long long*)(out + (size_t)o * 16512 + k0 + c) = *(const unsigned long long*)pk;
  }
}

// layer 0: w2T0[o][kappa], kappa = 16k+i (i<11 valid; k=128 bias; rest 0), KT0=2080
__global__ void k_w2t0(const float* __restrict__ w2_0, const float* __restrict__ b2_0,
                       _Float16* __restrict__ w2T0) {
  int o = blockIdx.x, t = threadIdx.x;
  for (int kap = t; kap < 2080; kap += 256) {
    int k = kap >> 4, i = kap & 15;
    float v = 0.f;
    if (i < 11) {
      if (k < 128) v = w2_0[(size_t)k * 1408 + i * 128 + o];
      else if (k == 128) v = b2_0[i * 128 + o];
    }
    w2T0[(size_t)o * 2080 + kap] = (_Float16)v;
  }
}

// ---------------- MFMA message GEMM (f16, barrier-free K-loop) ----------------
// msg[e][o] = sum_kappa Z[e][kappa] * w2T[o][kappa]
//   L14: kappa = k*128 + i (k: h-col, i: x-col); L0: kappa = k*16 + i
// Block: 128 edges x 128 outputs. Wave w: all 128 edge-rows (8 M-tiles) x 32 cols
// (2 N-tiles) -> B slab is read with zero cross-wave redundancy and each
// ds_read_b128 feeds 8 MFMAs. B staged wave-private in FRAGMENT ORDER via
// pre-swizzled global source + linear global_load_lds dest -> no LDS bank
// conflicts, no K-loop barriers; counted s_waitcnt vmcnt(2) does the sync.
template <bool L0>
__global__ __launch_bounds__(256, 2) void k_mma2(
    const _Float16* __restrict__ xh,   // L0: [NN][16] else [NN][128]
    const _Float16* __restrict__ hb,   // [NE][128] (this layer)
    const _Float16* __restrict__ w2T,  // [128][KT]
    const int* __restrict__ src,
    _Float16* __restrict__ msgp) {     // [SK][NE][128] partials
  constexpr int KT = L0 ? 2080 : 16512;
  constexpr int NWIN = L0 ? 1 : 4;
  __shared__ _Float16 Bs[2][4096];     // 2 x 8KB, fragment-order, wave-private quarters
  __shared__ _Float16 hTl[26][128];    // transposed h rows for this block's k-range

  const int tid = threadIdx.x;
  const int e0 = blockIdx.x * 128;
  const int w = tid >> 6, l = tid & 63, l16 = l & 15, g = l >> 4;

  int k0, nk;
  if constexpr (L0) {
    k0 = blockIdx.y * 13; nk = 13;     // c-chunks (each = 2 h-cols x 16 i)
  } else {
    int sk = blockIdx.y;
    if (sk == 0) { k0 = 0; nk = 9; } else { k0 = 9 + (sk - 1) * 8; nk = 8; }
  }
  const int kb = L0 ? k0 * 2 : k0;     // first h-col staged in hTl

  // this lane's 8 M-row node ids
  int nd[8];
#pragma unroll
  for (int mt = 0; mt < 8; ++mt) nd[mt] = src[e0 + mt * 16 + l16];

  // stage hTl (only this block's k-range; synth rows: k==128 -> 1.0, k==129 -> 0)
  {
    const int nrow = L0 ? 26 : nk;
    for (int idx = tid; idx < nrow * 128; idx += 256) {
      int kk = idx >> 7, m = idx & 127;
      int k = kb + kk;
      _Float16 v;
      if (k < 128) v = hb[(size_t)(e0 + m) * 128 + k];
      else v = (k == 128) ? (_Float16)1.0f : (_Float16)0.0f;
      hTl[kk][m] = v;
    }
  }

  // wave-private fragment-order B staging: load j2 covers N-tile ntg = w*2+j2;
  // LDS dest = uniform base + lane*16 (linear); global source pre-swizzled.
  auto stageB = [&](int buf, int kap0) {
#pragma unroll
    for (int j2 = 0; j2 < 2; ++j2) {
      int ntg = w * 2 + j2;
      const _Float16* gp = w2T + (size_t)(ntg * 16 + l16) * KT + kap0 + g * 8;
      GLOAD_LDS16(gp, &Bs[buf][(w * 128 + j2 * 64) * 8]);
    }
  };

  stageB(0, L0 ? k0 * 32 : k0 * 128);
  __syncthreads();   // hTl ready (also drains prologue stage)

  f32x4 acc[8][2];
#pragma unroll
  for (int mt = 0; mt < 8; ++mt)
#pragma unroll
    for (int jj = 0; jj < 2; ++jj) acc[mt][jj] = (f32x4){0.f, 0.f, 0.f, 0.f};

  int buf = 0;
  for (int win = 0; win < NWIN; ++win) {
    // per-window x slices (per-lane register cache, 8 rows x 8 f16)
    f16x8 xw[8];
#pragma unroll
    for (int mt = 0; mt < 8; ++mt) {
      const _Float16* xp = L0 ? (xh + (size_t)nd[mt] * 16 + (g & 1) * 8)
                              : (xh + (size_t)nd[mt] * 128 + win * 32 + g * 8);
      xw[mt] = *(const f16x8*)xp;
    }
    for (int j = 0; j < nk; ++j) {
      const bool last = (j + 1 == nk) && (win + 1 == NWIN);
      if (j + 1 < nk) {
        stageB(buf ^ 1, L0 ? (k0 + j + 1) * 32 : (k0 + j + 1) * 128 + win * 32);
      } else if (win + 1 < NWIN) {
        stageB(buf ^ 1, k0 * 128 + (win + 1) * 32);
      }
      if (last) { asm volatile("s_waitcnt vmcnt(0)" ::: "memory"); }
      else      { asm volatile("s_waitcnt vmcnt(2)" ::: "memory"); }
      __builtin_amdgcn_sched_barrier(0);

      f16x8 bv0 = *(const f16x8*)&Bs[buf][(size_t)(w * 2 + 0) * 512 + l * 8];
      f16x8 bv1 = *(const f16x8*)&Bs[buf][(size_t)(w * 2 + 1) * 512 + l * 8];
#pragma unroll
      for (int mt = 0; mt < 8; ++mt) {
        _Float16 hh;
        if constexpr (L0) hh = hTl[2 * j + (g >> 1)][mt * 16 + l16];
        else              hh = hTl[j][mt * 16 + l16];
        f16x8 hv = {hh, hh, hh, hh, hh, hh, hh, hh};
        f16x8 av = xw[mt] * hv;   // 4 x v_pk_mul_f16
        acc[mt][0] = __builtin_amdgcn_mfma_f32_16x16x32_f16(av, bv0, acc[mt][0], 0, 0, 0);
        acc[mt][1] = __builtin_amdgcn_mfma_f32_16x16x32_f16(av, bv1, acc[mt][1], 0, 0, 0);
      }
      buf ^= 1;
    }
  }

  // epilogue: C/D row = 4g + r, col = l16 (verified layout)
  _Float16* mp = msgp + ((size_t)blockIdx.y * NE + e0) * 128;
#pragma unroll
  for (int mt = 0; mt < 8; ++mt)
#pragma unroll
    for (int jj = 0; jj < 2; ++jj)
#pragma unroll
      for (int r = 0; r < 4; ++r) {
        int row = mt * 16 + 4 * g + r;
        mp[(size_t)row * 128 + w * 32 + jj * 16 + l16] = (_Float16)acc[mt][jj][r];
      }
}

// ---------------- fused: split-K reduce + scatter-mean + root + BN + ReLU (+res) ----------------
template <int INR, int NSK>
__global__ void k_au(const _Float16* __restrict__ msgp, const int* __restrict__ rowptr,
                     const int* __restrict__ elist, const float* __restrict__ xin,
                     const float* __restrict__ root, const float* __restrict__ bias,
                     const float* __restrict__ bg, const float* __restrict__ bb,
                     const float* __restrict__ bm, const float* __restrict__ bv,
                     const float* __restrict__ h_prev, float* __restrict__ h_out,
                     _Float16* __restrict__ h_out_h) {
  int n = blockIdx.x, t = threadIdx.x;  // 128 threads
  __shared__ float xr[INR];
  if (t < INR) xr[t] = xin[(size_t)n * INR + t];
  int beg = rowptr[n], end = rowptr[n + 1];
  float v = 0.f;
  for (int j = beg; j < end; ++j) {
    int e = elist[j];
#pragma unroll
    for (int s = 0; s < NSK; ++s) v += (float)msgp[((size_t)s * NE + e) * HD + t];
  }
  v /= fmaxf((float)(end - beg), 1.f);
  __syncthreads();
  float acc = v + bias[t];
#pragma unroll 8
  for (int k = 0; k < INR; ++k) acc += xr[k] * root[(size_t)k * HD + t];
  float bn = (acc - bm[t]) * rsqrtf(bv[t] + 1e-5f) * bg[t] + bb[t];
  float r = fmaxf(bn, 0.f);
  float val = h_prev ? (h_prev[(size_t)n * HD + t] + r) : r;
  h_out[(size_t)n * HD + t] = val;
  h_out_h[(size_t)n * HD + t] = (_Float16)val;
}

// ---------------- fused global mean pool + readout MLP ----------------
__global__ void k_poolread(const float* __restrict__ h, const int* __restrict__ gstart,
                           const float* __restrict__ w1, const float* __restrict__ b1,
                           const float* __restrict__ w2, const float* __restrict__ b2,
                           float* __restrict__ out) {
  int g = blockIdx.x, t = threadIdx.x;  // 128 threads
  __shared__ float row[HD];
  int beg = gstart[g], end = gstart[g + 1];
  float v = 0.f;
  for (int n = beg; n < end; ++n) v += h[(size_t)n * HD + t];
  row[t] = v / fmaxf((float)(end - beg), 1.f);
  __syncthreads();
  if (t < 64) {
    float acc = b1[t];
#pragma unroll 8
    for (int k = 0; k < HD; ++k) acc += row[k] * w1[(size_t)k * 64 + t];
    float vv = fmaxf(acc, 0.f) * w2[t];
#pragma unroll
    for (int off = 32; off > 0; off >>= 1) vv += __shfl_down(vv, off);
    if (t == 0) out[g] = vv + b2[0];
  }
}

extern "C" void kernel_launch(void* const* d_in, const int* in_sizes, int n_in,
                              void* d_out, int out_size, void* d_ws, size_t ws_size,
                              hipStream_t stream) {
  const float* x      = (const float*)d_in[0];
  const float* ea     = (const float*)d_in[1];
  const int*   eidx   = (const int*)d_in[2];
  const int*   batch  = (const int*)d_in[3];
  const float* w1_0   = (const float*)d_in[4];
  const float* b1_0   = (const float*)d_in[5];
  const float* w2_0   = (const float*)d_in[6];
  const float* b2_0   = (const float*)d_in[7];
  const float* root_0 = (const float*)d_in[8];
  const float* bias_0 = (const float*)d_in[9];
  const float* bn_g0  = (const float*)d_in[10];
  const float* bn_b0  = (const float*)d_in[11];
  const float* bn_m0  = (const float*)d_in[12];
  const float* bn_v0  = (const float*)d_in[13];
  const float* w1_s   = (const float*)d_in[14];
  const float* b1_s   = (const float*)d_in[15];
  const float* w2_s   = (const float*)d_in[16];
  const float* b2_s   = (const float*)d_in[17];
  const float* root_s = (const float*)d_in[18];
  const float* bias_s = (const float*)d_in[19];
  const float* bn_gs  = (const float*)d_in[20];
  const float* bn_bs  = (const float*)d_in[21];
  const float* bn_ms  = (const float*)d_in[22];
  const float* bn_vs  = (const float*)d_in[23];
  const float* lin1_w = (const float*)d_in[24];
  const float* lin1_b = (const float*)d_in[25];
  const float* lin2_w = (const float*)d_in[26];
  const float* lin2_b = (const float*)d_in[27];
  float* out = (float*)d_out;

  char* wsb = (char*)d_ws;
  size_t off = 0;
  auto alloc = [&](size_t bytes) { void* p = wsb + off; off = (off + bytes + 255) & ~(size_t)255; return p; };
  int*      rowptr   = (int*)alloc((NN + 4) * 4);
  int*      elist    = (int*)alloc(NE * 4);
  int*      gstart   = (int*)alloc((NG + 4) * 4);
  int*      hist     = (int*)alloc((size_t)NCH * NN * 4);
  int*      chunkoff = (int*)alloc((size_t)NCH * NN * 4);
  _Float16* hbf      = (_Float16*)alloc((size_t)5 * NE * HD * 2);
  _Float16* x16      = (_Float16*)alloc((size_t)NN * 16 * 2);
  _Float16* w2T0     = (_Float16*)alloc((size_t)128 * 2080 * 2);
  _Float16* w2T      = (_Float16*)alloc((size_t)4 * 128 * 16512 * 2);
  float*    hnA      = (float*)alloc((size_t)NN * HD * 4);
  float*    hnB      = (float*)alloc((size_t)NN * HD * 4);
  _Float16* hnAh     = (_Float16*)alloc((size_t)NN * HD * 2);
  _Float16* hnBh     = (_Float16*)alloc((size_t)NN * HD * 2);
  _Float16* msgp     = (_Float16*)alloc((size_t)SKM * NE * HD * 2);

  const int* src = eidx;
  const int* dstp = eidx + NE;

  hipMemsetAsync(hist, 0, (size_t)NCH * NN * 4, stream);
  k_count<<<dim3(16), 256, 0, stream>>>(dstp, hist);
  k_scan2<<<1, 1024, 0, stream>>>(hist, rowptr, chunkoff, batch, gstart);
  k_fill2<<<dim3(NCH), 64, 0, stream>>>(dstp, chunkoff, elist);
  k_hallpad<<<dim3(10368), 256, 0, stream>>>(ea, w1_0, b1_0, w1_s, b1_s, x, hbf, x16);
  k_w2t0<<<dim3(128), 256, 0, stream>>>(w2_0, b2_0, w2T0);
  k_w2t<<<dim3(16512 / 64, 2, 4), 256, 0, stream>>>(w2_s, b2_s, w2T);

  // layer 0
  k_mma2<true><<<dim3(NE / 128, SK0), 256, 0, stream>>>(x16, hbf, w2T0, src, msgp);
  k_au<11, SK0><<<NN, HD, 0, stream>>>(msgp, rowptr, elist, x, root_0, bias_0,
                                       bn_g0, bn_b0, bn_m0, bn_v0, nullptr, hnA, hnAh);

  float* cur = hnA;  _Float16* curh = hnAh;
  float* nxt = hnB;  _Float16* nxth = hnBh;
  for (int l = 1; l <= 4; ++l) {
    const _Float16* w2Tl = w2T + (size_t)(l - 1) * 128 * 16512;
    k_mma2<false><<<dim3(NE / 128, SKM), 256, 0, stream>>>(
        curh, hbf + (size_t)l * NE * HD, w2Tl, src, msgp);
    k_au<128, SKM><<<NN, HD, 0, stream>>>(msgp, rowptr, elist, cur,
                                          root_s + (size_t)(l - 1) * HD * HD,
                                          bias_s + (size_t)(l - 1) * HD,
                                          bn_gs + (size_t)(l - 1) * HD, bn_bs + (size_t)(l - 1) * HD,
                                          bn_ms + (size_t)(l - 1) * HD, bn_vs + (size_t)(l - 1) * HD,
                                          cur, nxt, nxth);
    float* tf = cur; cur = nxt; nxt = tf;
    _Float16* th = curh; curh = nxth; nxth = th;
  }

  k_poolread<<<NG, HD, 0, stream>>>(cur, gstart, lin1_w, lin1_b, lin2_w, lin2_b, out);
}

// Round 5
// 237.298 us; speedup vs baseline: 6.5134x; 1.0774x over previous
//
#include <hip/hip_runtime.h>
#include <cstdint>
#include <cstddef>

#define NN 2048   // nodes
#define NE 4096   // edges
#define NG 128    // graphs
#define HD 128    // hidden
#define SKM 16    // split-K blocks layers 1-4 (129 h-cols: 9 + 15x8)
#define SK0 5     // split-K blocks layer 0 (65 c-chunks: 5x13)
#define NCH 64    // CSR sort chunks
#define CHE 64    // edges per chunk

typedef __attribute__((ext_vector_type(8))) _Float16 f16x8;
typedef __attribute__((ext_vector_type(4))) float f32x4;

#define GLOAD_LDS16(gptr, lptr)                                                          \
  __builtin_amdgcn_global_load_lds((const __attribute__((address_space(1))) unsigned int*)(gptr), \
                                   (__attribute__((address_space(3))) unsigned int*)(lptr), 16, 0, 0)

// ---------------- fused prep: count-hist + edge-MLP h + x-pad + w2T0 + w2T ----------------
__global__ __launch_bounds__(256) void k_prep(
    const float* __restrict__ ea,
    const float* __restrict__ w1_0, const float* __restrict__ b1_0,
    const float* __restrict__ w1_s, const float* __restrict__ b1_s,
    const float* __restrict__ x,
    const float* __restrict__ w2_0, const float* __restrict__ b2_0,
    const float* __restrict__ w2s, const float* __restrict__ b2s,
    const int* __restrict__ dst, int* __restrict__ hist,
    _Float16* __restrict__ hb, _Float16* __restrict__ x16,
    _Float16* __restrict__ w2T0, _Float16* __restrict__ w2T) {
  __shared__ float s[64][65];
  const int bid = blockIdx.x, t = threadIdx.x;

  if (bid < 10240) {
    // edge MLP h for all 5 layers
    int idx = bid * 256 + t;             // l*2^19 + e*128 + c
    int c = idx & (HD - 1);
    int e = (idx >> 7) & (NE - 1);
    int l = idx >> 19;
    const float* w1 = (l == 0) ? w1_0 : (w1_s + (size_t)(l - 1) * 4 * HD);
    const float* b1 = (l == 0) ? b1_0 : (b1_s + (size_t)(l - 1) * HD);
    float4 a = *(const float4*)(ea + (size_t)e * 4);
    float v = b1[c] + a.x * w1[c] + a.y * w1[HD + c] + a.z * w1[2 * HD + c] + a.w * w1[3 * HD + c];
    hb[idx] = (_Float16)fmaxf(v, 0.f);
  } else if (bid < 10368) {
    // pad x [2048][11] f32 -> [2048][16] f16
    int idx = (bid - 10240) * 256 + t;
    int n = idx >> 4, i = idx & 15;
    x16[idx] = (_Float16)(i < 11 ? x[(size_t)n * 11 + i] : 0.f);
  } else if (bid < 10496) {
    // layer-0 weight: w2T0[o][kappa], kappa = 16k+i (i<11 valid; k=128 bias), KT0=2080
    int o = bid - 10368;
    for (int kap = t; kap < 2080; kap += 256) {
      int k = kap >> 4, i = kap & 15;
      float v = 0.f;
      if (i < 11) {
        if (k < 128) v = w2_0[(size_t)k * 1408 + i * 128 + o];
        else if (k == 128) v = b2_0[i * 128 + o];
      }
      w2T0[(size_t)o * 2080 + kap] = (_Float16)v;
    }
  } else if (bid < 12560) {
    // layers 1-4: w2T[l][o][kappa], kappa=k*128+i (<16384 w2 flat; >=16384 b2 rows)
    int idx2 = bid - 10496;              // 0..2063 = l(4) x ob(2) x kb(258)
    int l = idx2 / 516;
    int rem = idx2 - l * 516;
    int ob = rem / 258;
    int kb = rem - ob * 258;
    const float* w2 = w2s + (size_t)l * 16384 * 128;
    const float* b2 = b2s + (size_t)l * 128 * 128;
    _Float16* out = w2T + (size_t)l * 128 * 16512;
    int k0 = kb * 64, o0 = ob * 64;
    int r = t >> 4, c4 = (t & 15) * 4;
#pragma unroll
    for (int it = 0; it < 4; ++it) {
      int kk = k0 + r + it * 16;
      const float* srcp = (kk < 16384) ? (w2 + (size_t)kk * 128 + o0 + c4)
                                       : (b2 + (size_t)(kk - 16384) * 128 + o0 + c4);
      *(float4*)&s[r + it * 16][c4] = *(const float4*)srcp;
    }
    __syncthreads();
    int rr = t >> 3, c8 = (t & 7) * 8;
#pragma unroll
    for (int it = 0; it < 2; ++it) {
      int ol = rr + it * 32;
      _Float16 pk[8];
#pragma unroll
      for (int j = 0; j < 8; ++j) pk[j] = (_Float16)s[c8 + j][ol];
      *(f16x8*)(out + (size_t)(o0 + ol) * 16512 + k0 + c8) = *(const f16x8*)pk;
    }
  } else {
    // per-chunk histogram (int atomics: deterministic)
    int e = (bid - 12560) * 256 + t;
    if (e < NE) atomicAdd(&hist[(e >> 6) * NN + dst[e]], 1);
  }
}

// ---------------- counts + scan -> rowptr + chunkoff + graph bounds ----------------
__global__ __launch_bounds__(1024) void k_scan2(const int* __restrict__ hist,
                                                int* __restrict__ rowptr,
                                                int* __restrict__ chunkoff,
                                                const int* __restrict__ batch,
                                                int* __restrict__ gstart) {
  __shared__ int s[NN];
  int t = threadIdx.x;
  int c0 = 0, c1 = 0;
  for (int c = 0; c < NCH; ++c) { c0 += hist[c * NN + t]; c1 += hist[c * NN + t + 1024]; }
  s[t] = c0; s[t + 1024] = c1;
  __syncthreads();
  for (int d = 1; d < NN; d <<= 1) {
    int a0 = s[t], a1 = s[t + 1024];
    int v0 = (t >= d) ? s[t - d] : 0;
    int v1 = (t + 1024 >= d) ? s[t + 1024 - d] : 0;
    __syncthreads();
    s[t] = a0 + v0; s[t + 1024] = a1 + v1;
    __syncthreads();
  }
  rowptr[t + 1] = s[t]; rowptr[t + 1025] = s[t + 1024];
  if (t == 0) rowptr[0] = 0;
  int run0 = s[t] - c0, run1 = s[t + 1024] - c1;   // exclusive prefix
  for (int c = 0; c < NCH; ++c) {
    chunkoff[c * NN + t] = run0;        run0 += hist[c * NN + t];
    chunkoff[c * NN + t + 1024] = run1; run1 += hist[c * NN + t + 1024];
  }
  if (t <= NG) {
    int lo = 0, hi = NN;
    while (lo < hi) { int mid = (lo + hi) >> 1; if (batch[mid] < t) lo = mid + 1; else hi = mid; }
    gstart[t] = lo;
  }
}

__global__ __launch_bounds__(64) void k_fill2(const int* __restrict__ dst,
                                              const int* __restrict__ chunkoff,
                                              int* __restrict__ elist) {
  __shared__ int sd[CHE];
  int c = blockIdx.x, t = threadIdx.x;
  int e = c * CHE + t;
  int dv = dst[e];
  sd[t] = dv;
  __syncthreads();
  int lrank = 0;
  for (int j = 0; j < t; ++j) lrank += (sd[j] == dv) ? 1 : 0;
  elist[chunkoff[c * NN + dv] + lrank] = e;   // stable order -> deterministic sums
}

// ---------------- layer-0 MFMA GEMM (R4 structure, proven) ----------------
__global__ __launch_bounds__(256, 2) void k_mma0(
    const _Float16* __restrict__ xh,   // [NN][16] f16
    const _Float16* __restrict__ hb,   // [NE][128] f16 (layer 0)
    const _Float16* __restrict__ w2T,  // [128][2080]
    const int* __restrict__ src,
    _Float16* __restrict__ msgp) {
  constexpr int KT = 2080;
  __shared__ _Float16 Bs[2][4096];
  __shared__ _Float16 hTl[26][128];

  const int tid = threadIdx.x;
  const int e0 = blockIdx.x * 128;
  const int w = tid >> 6, l = tid & 63, l16 = l & 15, g = l >> 4;

  const int k0 = blockIdx.y * 13, nk = 13;
  const int kb = k0 * 2;

  int nd[8];
#pragma unroll
  for (int mt = 0; mt < 8; ++mt) nd[mt] = src[e0 + mt * 16 + l16];

  for (int idx = tid; idx < 26 * 128; idx += 256) {
    int kk = idx >> 7, m = idx & 127;
    int k = kb + kk;
    _Float16 v;
    if (k < 128) v = hb[(size_t)(e0 + m) * 128 + k];
    else v = (k == 128) ? (_Float16)1.0f : (_Float16)0.0f;
    hTl[kk][m] = v;
  }

  f16x8 xr[8];
#pragma unroll
  for (int mt = 0; mt < 8; ++mt)
    xr[mt] = *(const f16x8*)(xh + (size_t)nd[mt] * 16 + (g & 1) * 8);

  auto stageB = [&](int buf, int c) {
    const int kap0 = c * 32;
#pragma unroll
    for (int j2 = 0; j2 < 2; ++j2) {
      int ntg = w * 2 + j2;
      const _Float16* gp = w2T + (size_t)(ntg * 16 + l16) * KT + kap0 + g * 8;
      GLOAD_LDS16(gp, &Bs[buf][(w * 128 + j2 * 64) * 8]);
    }
  };

  stageB(0, k0);
  __syncthreads();

  f32x4 acc[8][2];
#pragma unroll
  for (int mt = 0; mt < 8; ++mt)
#pragma unroll
    for (int jj = 0; jj < 2; ++jj) acc[mt][jj] = (f32x4){0.f, 0.f, 0.f, 0.f};

  int buf = 0;
  for (int j = 0; j < nk; ++j) {
    if (j + 1 < nk) {
      stageB(buf ^ 1, k0 + j + 1);
      asm volatile("s_waitcnt vmcnt(2)" ::: "memory");
    } else {
      asm volatile("s_waitcnt vmcnt(0)" ::: "memory");
    }
    __builtin_amdgcn_sched_barrier(0);

    f16x8 bv0 = *(const f16x8*)&Bs[buf][(size_t)(w * 2 + 0) * 512 + l * 8];
    f16x8 bv1 = *(const f16x8*)&Bs[buf][(size_t)(w * 2 + 1) * 512 + l * 8];
#pragma unroll
    for (int mt = 0; mt < 8; ++mt) {
      _Float16 hh = hTl[2 * j + (g >> 1)][mt * 16 + l16];
      f16x8 hv = {hh, hh, hh, hh, hh, hh, hh, hh};
      f16x8 av = xr[mt] * hv;
      acc[mt][0] = __builtin_amdgcn_mfma_f32_16x16x32_f16(av, bv0, acc[mt][0], 0, 0, 0);
      acc[mt][1] = __builtin_amdgcn_mfma_f32_16x16x32_f16(av, bv1, acc[mt][1], 0, 0, 0);
    }
    buf ^= 1;
    __syncthreads();
  }

  _Float16* mp = msgp + ((size_t)blockIdx.y * NE + e0) * 128;
#pragma unroll
  for (int mt = 0; mt < 8; ++mt)
#pragma unroll
    for (int jj = 0; jj < 2; ++jj)
#pragma unroll
      for (int r = 0; r < 4; ++r) {
        int row = mt * 16 + 4 * g + r;
        mp[(size_t)row * 128 + w * 32 + jj * 16 + l16] = (_Float16)acc[mt][jj][r];
      }
}

// ---------------- layers 1-4 MFMA GEMM: BM=256, shared 4-buf staging ----------------
// Block: 256 edges x 128 out, K-slice = nk h-cols (8/9). 8 waves = 4Mg x 2Ng;
// wave = 4 M-tiles x 4 N-tiles. B slab (128 rows x 32 kappa) staged cooperatively
// (wave w stages rows w*16..w*16+16 => zero redundancy), lane->(g,row) permuted
// layout so ds_read_b128 hits the 8-cycle bank floor. 4-deep ring + counted
// vmcnt + raw s_barrier; grid flat bid = eb*16+sk packs same-sk blocks per XCD.
__global__ __launch_bounds__(512, 2) void k_mma3(
    const _Float16* __restrict__ xh,   // [NN][128]
    const _Float16* __restrict__ hb,   // [NE][128] (this layer)
    const _Float16* __restrict__ w2T,  // [128][16512]
    const int* __restrict__ src,
    _Float16* __restrict__ msgp) {     // [SK][NE][128]
  constexpr int KT = 16512;
  __shared__ __align__(16) _Float16 Bs[4][4096];
  __shared__ _Float16 hTl[9][256];

  const int tid = threadIdx.x;
  const int w = tid >> 6, l = tid & 63, l16 = l & 15, g = l >> 4;
  const int bid = blockIdx.x;
  const int eb = bid >> 4, sk = bid & 15;
  const int e0 = eb * 256;
  const int mg = w & 3, ng = w >> 2;

  int k0, nk;
  if (sk == 0) { k0 = 0; nk = 9; } else { k0 = 9 + (sk - 1) * 8; nk = 8; }
  const int nsteps = nk * 4;

  auto stageB = [&](int s) {
    const int jk = s >> 2, win = s & 3;
    const int kap0 = (k0 + jk) * 128 + win * 32;
    const _Float16* gp = w2T + (size_t)(w * 16 + l16) * KT + kap0 + g * 8;
    GLOAD_LDS16(gp, &Bs[s & 3][w * 512]);
  };

  stageB(0);
  stageB(1);

  int nd[4];
#pragma unroll
  for (int mt = 0; mt < 4; ++mt) nd[mt] = src[e0 + mg * 64 + mt * 16 + l16];
  f16x8 xw[4][4];
#pragma unroll
  for (int mt = 0; mt < 4; ++mt)
#pragma unroll
    for (int win = 0; win < 4; ++win)
      xw[mt][win] = *(const f16x8*)(xh + (size_t)nd[mt] * 128 + win * 32 + g * 8);

  for (int idx = tid; idx < nk * 256; idx += 512) {
    int jk = idx >> 8, m = idx & 255;
    int k = k0 + jk;
    hTl[jk][m] = (k < 128) ? hb[(size_t)(e0 + m) * 128 + k]
                           : (_Float16)(k == 128 ? 1.0f : 0.0f);
  }
  __syncthreads();   // hTl ready; prologue stages drained

  f32x4 acc[4][4];
#pragma unroll
  for (int mt = 0; mt < 4; ++mt)
#pragma unroll
    for (int j2 = 0; j2 < 4; ++j2) acc[mt][j2] = (f32x4){0.f, 0.f, 0.f, 0.f};

  for (int jk = 0; jk < nk; ++jk) {
    _Float16 hv[4];
#pragma unroll
    for (int mt = 0; mt < 4; ++mt) hv[mt] = hTl[jk][mg * 64 + mt * 16 + l16];
#pragma unroll
    for (int win = 0; win < 4; ++win) {
      const int s = jk * 4 + win;
      if (s + 2 < nsteps) {
        stageB(s + 2);
        asm volatile("s_waitcnt vmcnt(2)" ::: "memory");
      } else if (s + 2 == nsteps) {
        asm volatile("s_waitcnt vmcnt(1)" ::: "memory");
      } else {
        asm volatile("s_waitcnt vmcnt(0)" ::: "memory");
      }
      __builtin_amdgcn_s_barrier();

      const _Float16* bp = &Bs[win][ng * 2048 + g * 128 + l16 * 8];
      f16x8 bv0 = *(const f16x8*)(bp);
      f16x8 bv1 = *(const f16x8*)(bp + 512);
      f16x8 bv2 = *(const f16x8*)(bp + 1024);
      f16x8 bv3 = *(const f16x8*)(bp + 1536);
#pragma unroll
      for (int mt = 0; mt < 4; ++mt) {
        _Float16 hh = hv[mt];
        f16x8 hs = {hh, hh, hh, hh, hh, hh, hh, hh};
        f16x8 av = xw[mt][win] * hs;
        acc[mt][0] = __builtin_amdgcn_mfma_f32_16x16x32_f16(av, bv0, acc[mt][0], 0, 0, 0);
        acc[mt][1] = __builtin_amdgcn_mfma_f32_16x16x32_f16(av, bv1, acc[mt][1], 0, 0, 0);
        acc[mt][2] = __builtin_amdgcn_mfma_f32_16x16x32_f16(av, bv2, acc[mt][2], 0, 0, 0);
        acc[mt][3] = __builtin_amdgcn_mfma_f32_16x16x32_f16(av, bv3, acc[mt][3], 0, 0, 0);
      }
    }
  }

  // epilogue: C/D row = 4g + r, col = l16
  _Float16* mp = msgp + ((size_t)sk * NE + e0) * 128;
#pragma unroll
  for (int mt = 0; mt < 4; ++mt)
#pragma unroll
    for (int j2 = 0; j2 < 4; ++j2)
#pragma unroll
      for (int r = 0; r < 4; ++r) {
        int row = mg * 64 + mt * 16 + 4 * g + r;
        int col = (ng * 4 + j2) * 16 + l16;
        mp[(size_t)row * 128 + col] = (_Float16)acc[mt][j2][r];
      }
}

// ---------------- fused: split-K reduce + scatter-mean + root + BN + ReLU (+res) ----------------
template <int INR, int NSK>
__global__ void k_au(const _Float16* __restrict__ msgp, const int* __restrict__ rowptr,
                     const int* __restrict__ elist, const float* __restrict__ xin,
                     const float* __restrict__ root, const float* __restrict__ bias,
                     const float* __restrict__ bg, const float* __restrict__ bb,
                     const float* __restrict__ bm, const float* __restrict__ bv,
                     const float* __restrict__ h_prev, float* __restrict__ h_out,
                     _Float16* __restrict__ h_out_h) {
  int n = blockIdx.x, t = threadIdx.x;  // 128 threads
  __shared__ float xr[INR];
  if (t < INR) xr[t] = xin[(size_t)n * INR + t];
  int beg = rowptr[n], end = rowptr[n + 1];
  float v = 0.f;
  for (int j = beg; j < end; ++j) {
    int e = elist[j];
#pragma unroll
    for (int s = 0; s < NSK; ++s) v += (float)msgp[((size_t)s * NE + e) * HD + t];
  }
  v /= fmaxf((float)(end - beg), 1.f);
  __syncthreads();
  float acc = v + bias[t];
#pragma unroll 8
  for (int k = 0; k < INR; ++k) acc += xr[k] * root[(size_t)k * HD + t];
  float bn = (acc - bm[t]) * rsqrtf(bv[t] + 1e-5f) * bg[t] + bb[t];
  float r = fmaxf(bn, 0.f);
  float val = h_prev ? (h_prev[(size_t)n * HD + t] + r) : r;
  h_out[(size_t)n * HD + t] = val;
  h_out_h[(size_t)n * HD + t] = (_Float16)val;
}

// ---------------- fused global mean pool + readout MLP ----------------
__global__ void k_poolread(const float* __restrict__ h, const int* __restrict__ gstart,
                           const float* __restrict__ w1, const float* __restrict__ b1,
                           const float* __restrict__ w2, const float* __restrict__ b2,
                           float* __restrict__ out) {
  int g = blockIdx.x, t = threadIdx.x;  // 128 threads
  __shared__ float row[HD];
  int beg = gstart[g], end = gstart[g + 1];
  float v = 0.f;
  for (int n = beg; n < end; ++n) v += h[(size_t)n * HD + t];
  row[t] = v / fmaxf((float)(end - beg), 1.f);
  __syncthreads();
  if (t < 64) {
    float acc = b1[t];
#pragma unroll 8
    for (int k = 0; k < HD; ++k) acc += row[k] * w1[(size_t)k * 64 + t];
    float vv = fmaxf(acc, 0.f) * w2[t];
#pragma unroll
    for (int off = 32; off > 0; off >>= 1) vv += __shfl_down(vv, off);
    if (t == 0) out[g] = vv + b2[0];
  }
}

extern "C" void kernel_launch(void* const* d_in, const int* in_sizes, int n_in,
                              void* d_out, int out_size, void* d_ws, size_t ws_size,
                              hipStream_t stream) {
  const float* x      = (const float*)d_in[0];
  const float* ea     = (const float*)d_in[1];
  const int*   eidx   = (const int*)d_in[2];
  const int*   batch  = (const int*)d_in[3];
  const float* w1_0   = (const float*)d_in[4];
  const float* b1_0   = (const float*)d_in[5];
  const float* w2_0   = (const float*)d_in[6];
  const float* b2_0   = (const float*)d_in[7];
  const float* root_0 = (const float*)d_in[8];
  const float* bias_0 = (const float*)d_in[9];
  const float* bn_g0  = (const float*)d_in[10];
  const float* bn_b0  = (const float*)d_in[11];
  const float* bn_m0  = (const float*)d_in[12];
  const float* bn_v0  = (const float*)d_in[13];
  const float* w1_s   = (const float*)d_in[14];
  const float* b1_s   = (const float*)d_in[15];
  const float* w2_s   = (const float*)d_in[16];
  const float* b2_s   = (const float*)d_in[17];
  const float* root_s = (const float*)d_in[18];
  const float* bias_s = (const float*)d_in[19];
  const float* bn_gs  = (const float*)d_in[20];
  const float* bn_bs  = (const float*)d_in[21];
  const float* bn_ms  = (const float*)d_in[22];
  const float* bn_vs  = (const float*)d_in[23];
  const float* lin1_w = (const float*)d_in[24];
  const float* lin1_b = (const float*)d_in[25];
  const float* lin2_w = (const float*)d_in[26];
  const float* lin2_b = (const float*)d_in[27];
  float* out = (float*)d_out;

  char* wsb = (char*)d_ws;
  size_t off = 0;
  auto alloc = [&](size_t bytes) { void* p = wsb + off; off = (off + bytes + 255) & ~(size_t)255; return p; };
  int*      rowptr   = (int*)alloc((NN + 4) * 4);
  int*      elist    = (int*)alloc(NE * 4);
  int*      gstart   = (int*)alloc((NG + 4) * 4);
  int*      hist     = (int*)alloc((size_t)NCH * NN * 4);
  int*      chunkoff = (int*)alloc((size_t)NCH * NN * 4);
  _Float16* hbf      = (_Float16*)alloc((size_t)5 * NE * HD * 2);
  _Float16* x16      = (_Float16*)alloc((size_t)NN * 16 * 2);
  _Float16* w2T0     = (_Float16*)alloc((size_t)128 * 2080 * 2);
  _Float16* w2T      = (_Float16*)alloc((size_t)4 * 128 * 16512 * 2);
  float*    hnA      = (float*)alloc((size_t)NN * HD * 4);
  float*    hnB      = (float*)alloc((size_t)NN * HD * 4);
  _Float16* hnAh     = (_Float16*)alloc((size_t)NN * HD * 2);
  _Float16* hnBh     = (_Float16*)alloc((size_t)NN * HD * 2);
  _Float16* msgp     = (_Float16*)alloc((size_t)SKM * NE * HD * 2);

  const int* src = eidx;
  const int* dstp = eidx + NE;

  hipMemsetAsync(hist, 0, (size_t)NCH * NN * 4, stream);
  k_prep<<<dim3(12576), 256, 0, stream>>>(ea, w1_0, b1_0, w1_s, b1_s, x,
                                          w2_0, b2_0, w2_s, b2_s,
                                          dstp, hist, hbf, x16, w2T0, w2T);
  k_scan2<<<1, 1024, 0, stream>>>(hist, rowptr, chunkoff, batch, gstart);
  k_fill2<<<dim3(NCH), 64, 0, stream>>>(dstp, chunkoff, elist);

  // layer 0
  k_mma0<<<dim3(NE / 128, SK0), 256, 0, stream>>>(x16, hbf, w2T0, src, msgp);
  k_au<11, SK0><<<NN, HD, 0, stream>>>(msgp, rowptr, elist, x, root_0, bias_0,
                                       bn_g0, bn_b0, bn_m0, bn_v0, nullptr, hnA, hnAh);

  float* cur = hnA;  _Float16* curh = hnAh;
  float* nxt = hnB;  _Float16* nxth = hnBh;
  for (int l = 1; l <= 4; ++l) {
    const _Float16* w2Tl = w2T + (size_t)(l - 1) * 128 * 16512;
    k_mma3<<<dim3(256), 512, 0, stream>>>(curh, hbf + (size_t)l * NE * HD, w2Tl, src, msgp);
    k_au<128, SKM><<<NN, HD, 0, stream>>>(msgp, rowptr, elist, cur,
                                          root_s + (size_t)(l - 1) * HD * HD,
                                          bias_s + (size_t)(l - 1) * HD,
                                          bn_gs + (size_t)(l - 1) * HD, bn_bs + (size_t)(l - 1) * HD,
                                          bn_ms + (size_t)(l - 1) * HD, bn_vs + (size_t)(l - 1) * HD,
                                          cur, nxt, nxth);
    float* tf = cur; cur = nxt; nxt = tf;
    _Float16* th = curh; curh = nxth; nxth = th;
  }

  k_poolread<<<NG, HD, 0, stream>>>(cur, gstart, lin1_w, lin1_b, lin2_w, lin2_b, out);
}